// Round 1
// baseline (4077.153 us; speedup 1.0000x reference)
//
#include <hip/hip_runtime.h>
#include <math.h>

#define NDIM    256
#define DMODEL  512
#define DSTATE  16
#define LAYERS  4
#define KLEN    14
#define DINNER  1024
#define DTRANK  32
#define BATCH   8
#define TLEN    2000
#define LOUT    497
#define MROWS   (BATCH*LOUT)   // 3976
#define NCLS    41

// ---------------------------------------------------------------------------
// Gaussian smoothing over time: XS[b,t,d] = sum_j X[b,t-9+j,d] * k[j] (normalized)
// ---------------------------------------------------------------------------
__global__ __launch_bounds__(256) void smooth_kernel(const float* __restrict__ X,
                                                     float* __restrict__ XS)
{
    __shared__ float w[20];
    int tid = threadIdx.x;
    if (tid < 20) {
        float t = ((float)tid - 9.5f) * 0.5f;
        w[tid] = expf(-0.5f * t * t);
    }
    __syncthreads();
    float s = 0.f;
    #pragma unroll
    for (int j = 0; j < 20; j++) s += w[j];
    float inv = 1.f / s;

    int idx = blockIdx.x * 256 + tid;          // < 8*2000*256
    if (idx >= BATCH * TLEN * NDIM) return;
    int d  = idx & 255;
    int bt = idx >> 8;                         // b*2000 + t
    int b  = bt / TLEN;
    int tt = bt - b * TLEN;
    const float* Xb = X + ((size_t)b * TLEN) * NDIM + d;
    float acc = 0.f;
    #pragma unroll
    for (int j = 0; j < 20; j++) {
        int t2 = tt - 9 + j;
        if (t2 >= 0 && t2 < TLEN) acc += Xb[(size_t)t2 * NDIM] * w[j];
    }
    XS[idx] = acc * inv;
}

// ---------------------------------------------------------------------------
// Day transform: per-b GEMM (2000x256)@(256x256 K-major) + day bias + softsign
// ---------------------------------------------------------------------------
__global__ __launch_bounds__(256) void day_gemm(const float* __restrict__ XS,
                                                const float* __restrict__ day_w,
                                                const float* __restrict__ day_b,
                                                const int*   __restrict__ dayIdx,
                                                float* __restrict__ XD)
{
    __shared__ float As[16][132];
    __shared__ float Bs[16][68];
    int tid = threadIdx.x;
    int b   = blockIdx.z;
    int day = dayIdx[b];
    const float* A  = XS + (size_t)b * TLEN * NDIM;
    const float* W  = day_w + (size_t)day * NDIM * NDIM;   // (K=256, N=256) row-major
    const float* bi = day_b + (size_t)day * NDIM;
    float* C = XD + (size_t)b * TLEN * NDIM;

    int row0 = blockIdx.x * 128;
    int col0 = blockIdx.y * 64;

    int am = tid >> 1, ak = (tid & 1) * 8;
    bool aval = (row0 + am) < TLEN;
    const float* pA = A + (size_t)(row0 + am) * NDIM + ak;
    int bkk = tid >> 4;            // 0..15
    int bnn = (tid & 15) * 4;      // 0..60

    float acc[8][4];
    #pragma unroll
    for (int i = 0; i < 8; i++)
        #pragma unroll
        for (int j = 0; j < 4; j++) acc[i][j] = 0.f;

    int m0 = (tid & 15) * 8, n0 = (tid >> 4) * 4;

    for (int kt = 0; kt < NDIM; kt += 16) {
        float4 a0 = make_float4(0,0,0,0), a1 = a0;
        if (aval) { a0 = *(const float4*)(pA + kt); a1 = *(const float4*)(pA + kt + 4); }
        float4 b0 = *(const float4*)(W + (size_t)(kt + bkk) * NDIM + col0 + bnn);
        As[ak+0][am]=a0.x; As[ak+1][am]=a0.y; As[ak+2][am]=a0.z; As[ak+3][am]=a0.w;
        As[ak+4][am]=a1.x; As[ak+5][am]=a1.y; As[ak+6][am]=a1.z; As[ak+7][am]=a1.w;
        *(float4*)&Bs[bkk][bnn] = b0;
        __syncthreads();
        #pragma unroll
        for (int kk = 0; kk < 16; kk++) {
            const float4 bv = *(const float4*)&Bs[kk][n0];
            const float4 x0 = *(const float4*)&As[kk][m0];
            const float4 x1 = *(const float4*)&As[kk][m0+4];
            float av[8] = {x0.x,x0.y,x0.z,x0.w,x1.x,x1.y,x1.z,x1.w};
            float bw[4] = {bv.x,bv.y,bv.z,bv.w};
            #pragma unroll
            for (int i = 0; i < 8; i++)
                #pragma unroll
                for (int j = 0; j < 4; j++)
                    acc[i][j] = fmaf(av[i], bw[j], acc[i][j]);
        }
        __syncthreads();
    }
    #pragma unroll
    for (int i = 0; i < 8; i++) {
        int row = row0 + m0 + i;
        if (row < TLEN) {
            #pragma unroll
            for (int j = 0; j < 4; j++) {
                int col = col0 + n0 + j;
                float v = acc[i][j] + bi[col];
                v = v / (1.f + fabsf(v));
                C[(size_t)row * NDIM + col] = v;
            }
        }
    }
}

// ---------------------------------------------------------------------------
// lin_in GEMM with on-the-fly window gather:
//   H[m, o] = sum_kk XD[b, l*4 + kk%14, kk/14] * W[o, kk] + bias[o]
// m = b*497 + l ; K = 3584, N = 512
// ---------------------------------------------------------------------------
__global__ __launch_bounds__(256) void linin_gemm(const float* __restrict__ XD,
                                                  const float* __restrict__ W,
                                                  const float* __restrict__ bias,
                                                  float* __restrict__ H)
{
    __shared__ float As[16][132];
    __shared__ float Bs[16][68];
    int tid = threadIdx.x;
    int row0 = blockIdx.x * 128;
    int col0 = blockIdx.y * 64;

    int am = tid >> 1, ak = (tid & 1) * 8;
    int row = row0 + am;
    bool aval = row < MROWS;
    const float* pA = XD;
    if (aval) {
        unsigned ur = (unsigned)row;
        unsigned b  = ur / 497u;
        unsigned l  = ur - b * 497u;
        pA = XD + ((size_t)b * TLEN + (size_t)l * 4) * NDIM;
    }
    int bn = tid >> 2, bk = (tid & 3) * 4;
    const float* pW = W + (size_t)(col0 + bn) * 3584 + bk;

    float acc[8][4];
    #pragma unroll
    for (int i = 0; i < 8; i++)
        #pragma unroll
        for (int j = 0; j < 4; j++) acc[i][j] = 0.f;

    int m0 = (tid & 15) * 8, n0 = (tid >> 4) * 4;

    for (int kt = 0; kt < 3584; kt += 16) {
        float av[8];
        #pragma unroll
        for (int j = 0; j < 8; j++) {
            unsigned kk = (unsigned)(kt + ak + j);
            unsigned dd = kk / 14u;
            unsigned r  = kk - dd * 14u;
            av[j] = aval ? pA[(size_t)r * NDIM + dd] : 0.f;
        }
        float4 b0 = *(const float4*)(pW + kt);
        #pragma unroll
        for (int j = 0; j < 8; j++) As[ak+j][am] = av[j];
        Bs[bk+0][bn]=b0.x; Bs[bk+1][bn]=b0.y; Bs[bk+2][bn]=b0.z; Bs[bk+3][bn]=b0.w;
        __syncthreads();
        #pragma unroll
        for (int kk = 0; kk < 16; kk++) {
            const float4 bv = *(const float4*)&Bs[kk][n0];
            const float4 x0 = *(const float4*)&As[kk][m0];
            const float4 x1 = *(const float4*)&As[kk][m0+4];
            float a8[8] = {x0.x,x0.y,x0.z,x0.w,x1.x,x1.y,x1.z,x1.w};
            float b4[4] = {bv.x,bv.y,bv.z,bv.w};
            #pragma unroll
            for (int i = 0; i < 8; i++)
                #pragma unroll
                for (int j = 0; j < 4; j++)
                    acc[i][j] = fmaf(a8[i], b4[j], acc[i][j]);
        }
        __syncthreads();
    }
    #pragma unroll
    for (int i = 0; i < 8; i++) {
        int r2 = row0 + m0 + i;
        if (r2 < MROWS) {
            #pragma unroll
            for (int j = 0; j < 4; j++) {
                int col = col0 + n0 + j;
                H[(size_t)r2 * DMODEL + col] = acc[i][j] + bias[col];
            }
        }
    }
}

// ---------------------------------------------------------------------------
// Generic C = A(MxK,row) @ W(NxK,row)^T, tile 128x64, 8x4 microtile.
// EPI: 0 none, 1 +bias, 2 +bias then softplus
// ---------------------------------------------------------------------------
template<int EPI>
__global__ __launch_bounds__(256) void gemm_bt(const float* __restrict__ A, int lda,
                                               const float* __restrict__ W, int ldb,
                                               float* __restrict__ C, int ldc,
                                               const float* __restrict__ bias,
                                               int M, int N, int K)
{
    __shared__ float As[16][132];
    __shared__ float Bs[16][68];
    int tid = threadIdx.x;
    int row0 = blockIdx.x * 128;
    int col0 = blockIdx.y * 64;

    int am = tid >> 1, ak = (tid & 1) * 8;
    bool aval = (row0 + am) < M;
    const float* pA = A + (size_t)(row0 + am) * lda + ak;
    int bn = tid >> 2, bk = (tid & 3) * 4;
    bool bval = (col0 + bn) < N;
    const float* pW = W + (size_t)(col0 + bn) * ldb + bk;

    float acc[8][4];
    #pragma unroll
    for (int i = 0; i < 8; i++)
        #pragma unroll
        for (int j = 0; j < 4; j++) acc[i][j] = 0.f;

    int m0 = (tid & 15) * 8, n0 = (tid >> 4) * 4;

    for (int kt = 0; kt < K; kt += 16) {
        float4 a0 = make_float4(0,0,0,0), a1 = a0, b0 = a0;
        if (aval) { a0 = *(const float4*)(pA + kt); a1 = *(const float4*)(pA + kt + 4); }
        if (bval) { b0 = *(const float4*)(pW + kt); }
        As[ak+0][am]=a0.x; As[ak+1][am]=a0.y; As[ak+2][am]=a0.z; As[ak+3][am]=a0.w;
        As[ak+4][am]=a1.x; As[ak+5][am]=a1.y; As[ak+6][am]=a1.z; As[ak+7][am]=a1.w;
        Bs[bk+0][bn]=b0.x; Bs[bk+1][bn]=b0.y; Bs[bk+2][bn]=b0.z; Bs[bk+3][bn]=b0.w;
        __syncthreads();
        #pragma unroll
        for (int kk = 0; kk < 16; kk++) {
            const float4 bv = *(const float4*)&Bs[kk][n0];
            const float4 x0 = *(const float4*)&As[kk][m0];
            const float4 x1 = *(const float4*)&As[kk][m0+4];
            float a8[8] = {x0.x,x0.y,x0.z,x0.w,x1.x,x1.y,x1.z,x1.w};
            float b4[4] = {bv.x,bv.y,bv.z,bv.w};
            #pragma unroll
            for (int i = 0; i < 8; i++)
                #pragma unroll
                for (int j = 0; j < 4; j++)
                    acc[i][j] = fmaf(a8[i], b4[j], acc[i][j]);
        }
        __syncthreads();
    }
    #pragma unroll
    for (int i = 0; i < 8; i++) {
        int row = row0 + m0 + i;
        if (row < M) {
            #pragma unroll
            for (int j = 0; j < 4; j++) {
                int col = col0 + n0 + j;
                if (col < N) {
                    float v = acc[i][j];
                    if (EPI >= 1) v += bias[col];
                    if (EPI == 2) v = fmaxf(v, 0.f) + log1pf(expf(-fabsf(v)));
                    C[(size_t)row * ldc + col] = v;
                }
            }
        }
    }
}

// ---------------------------------------------------------------------------
// Causal depthwise conv (k=4, pad left 3) + bias + SiLU on x-half of XZ.
// ---------------------------------------------------------------------------
__global__ __launch_bounds__(256) void conv_silu_kernel(const float* __restrict__ XZ,
                                                        const float* __restrict__ cw,
                                                        const float* __restrict__ cb,
                                                        float* __restrict__ XC)
{
    int idx = blockIdx.x * 256 + threadIdx.x;   // 3976*1024
    if (idx >= MROWS * DINNER) return;
    int row = idx >> 10, c = idx & 1023;
    unsigned b = (unsigned)row / 497u;
    int l = row - (int)b * 497;
    float acc = cb[c];
    #pragma unroll
    for (int j = 0; j < 4; j++) {
        int lj = l - 3 + j;
        if (lj >= 0) acc += XZ[(size_t)(row - 3 + j) * 2048 + c] * cw[c * 4 + j];
    }
    float sig = 1.f / (1.f + expf(-acc));
    XC[idx] = acc * sig;
}

// ---------------------------------------------------------------------------
// Selective scan: one thread per (b,d), 16-state in registers, B/C via LDS.
// Gating fused; writes y in-place over DELTA.
// ---------------------------------------------------------------------------
__global__ __launch_bounds__(256) void scan_kernel(float* __restrict__ DELTA,
                                                   const float* __restrict__ XC,
                                                   const float* __restrict__ XZ,
                                                   const float* __restrict__ XDBC,
                                                   const float* __restrict__ Alog,
                                                   const float* __restrict__ Dp)
{
    __shared__ float sBC[32][32];
    int tid = threadIdx.x;
    int b = blockIdx.x >> 2;
    int d = (blockIdx.x & 3) * 256 + tid;
    int rowbase = b * LOUT;

    float a[DSTATE];
    #pragma unroll
    for (int n = 0; n < DSTATE; n++) a[n] = -expf(Alog[(size_t)d * DSTATE + n]);
    float dD = Dp[d];
    float s[DSTATE];
    #pragma unroll
    for (int n = 0; n < DSTATE; n++) s[n] = 0.f;

    int li = tid >> 3, lj = (tid & 7) * 4;

    for (int t0 = 0; t0 < LOUT; t0 += 32) {
        int tcnt = min(32, LOUT - t0);
        __syncthreads();
        if (li < tcnt) {
            float4 v = *(const float4*)(XDBC + (size_t)(rowbase + t0 + li) * 64 + 32 + lj);
            *(float4*)&sBC[li][lj] = v;
        }
        __syncthreads();
        for (int tt = 0; tt < tcnt; tt++) {
            size_t row = (size_t)(rowbase + t0 + tt);
            float dv = DELTA[row * DINNER + d];
            float xv = XC[row * DINNER + d];
            float zv = XZ[row * 2048 + DINNER + d];
            float dx = dv * xv;
            float y = 0.f;
            #pragma unroll
            for (int n = 0; n < DSTATE; n++) {
                float dA = expf(dv * a[n]);
                s[n] = fmaf(dA, s[n], dx * sBC[tt][n]);
                y = fmaf(s[n], sBC[tt][DSTATE + n], y);
            }
            float g = zv / (1.f + expf(-zv));
            DELTA[row * DINNER + d] = (y + xv * dD) * g;
        }
    }
}

// ---------------------------------------------------------------------------
extern "C" void kernel_launch(void* const* d_in, const int* in_sizes, int n_in,
                              void* d_out, int out_size, void* d_ws, size_t ws_size,
                              hipStream_t stream)
{
    const float* neuralInput = (const float*)d_in[0];
    const int*   dayIdx      = (const int*)  d_in[1];
    const float* day_w       = (const float*)d_in[2];
    const float* day_b       = (const float*)d_in[3];
    const float* lin_in_w    = (const float*)d_in[4];
    const float* lin_in_b    = (const float*)d_in[5];
    const float* in_proj_w   = (const float*)d_in[6];
    const float* conv_w      = (const float*)d_in[7];
    const float* conv_b      = (const float*)d_in[8];
    const float* x_proj_w    = (const float*)d_in[9];
    const float* dt_w        = (const float*)d_in[10];
    const float* dt_b        = (const float*)d_in[11];
    const float* A_log       = (const float*)d_in[12];
    const float* D_param     = (const float*)d_in[13];
    const float* out_proj_w  = (const float*)d_in[14];
    const float* fc_w        = (const float*)d_in[15];
    const float* fc_b        = (const float*)d_in[16];
    float* out = (float*)d_out;

    float* ws   = (float*)d_ws;
    float* xz   = ws;                      // 3976*2048 = 8,142,848
    float* xs   = xz + (size_t)MROWS*2048; // 8*2000*256 = 4,096,000 (xs, then xconv)
    float* xdly = xs + (size_t)BATCH*TLEN*NDIM; // 4,096,000 (xd, then delta/y)
    float* h    = xdly + (size_t)BATCH*TLEN*NDIM; // 3976*512
    float* xdbc = h + (size_t)MROWS*DMODEL;       // 3976*64
    float* xconv = xs;    // alias (xs dead after day transform)
    float* delta = xdly;  // alias (xd dead after lin_in)

    // 1. smooth
    smooth_kernel<<<dim3((BATCH*TLEN*NDIM)/256), 256, 0, stream>>>(neuralInput, xs);
    // 2. day transform
    day_gemm<<<dim3(16, 4, BATCH), 256, 0, stream>>>(xs, day_w, day_b, dayIdx, xdly);
    // 3. lin_in (windowed gather GEMM)
    linin_gemm<<<dim3(32, 8), 256, 0, stream>>>(xdly, lin_in_w, lin_in_b, h);

    for (int l = 0; l < LAYERS; l++) {
        const float* ipw = in_proj_w  + (size_t)l * 2048 * 512;
        const float* cwl = conv_w     + (size_t)l * DINNER * 4;
        const float* cbl = conv_b     + (size_t)l * DINNER;
        const float* xpw = x_proj_w   + (size_t)l * 64 * DINNER;
        const float* dtw = dt_w       + (size_t)l * DINNER * DTRANK;
        const float* dtb = dt_b       + (size_t)l * DINNER;
        const float* alg = A_log      + (size_t)l * DINNER * DSTATE;
        const float* dpl = D_param    + (size_t)l * DINNER;
        const float* opw = out_proj_w + (size_t)l * DMODEL * DINNER;

        // in_proj: (3976x512)@(2048x512)^T -> xz
        gemm_bt<0><<<dim3(32, 32), 256, 0, stream>>>(h, DMODEL, ipw, DMODEL,
                                                     xz, 2048, nullptr,
                                                     MROWS, 2048, DMODEL);
        // conv + silu -> xconv
        conv_silu_kernel<<<dim3((MROWS*DINNER)/256), 256, 0, stream>>>(xz, cwl, cbl, xconv);
        // x_proj: (3976x1024)@(64x1024)^T -> xdbc
        gemm_bt<0><<<dim3(32, 1), 256, 0, stream>>>(xconv, DINNER, xpw, DINNER,
                                                    xdbc, 64, nullptr,
                                                    MROWS, 64, DINNER);
        // dt: (3976x32 lda=64)@(1024x32)^T + bias, softplus -> delta
        gemm_bt<2><<<dim3(32, 16), 256, 0, stream>>>(xdbc, 64, dtw, DTRANK,
                                                     delta, DINNER, dtb,
                                                     MROWS, DINNER, DTRANK);
        // scan (+ D skip + silu(z) gate), y in-place over delta
        scan_kernel<<<dim3(32), 256, 0, stream>>>(delta, xconv, xz, xdbc, alg, dpl);
        // out_proj: (3976x1024)@(512x1024)^T -> h
        gemm_bt<0><<<dim3(32, 8), 256, 0, stream>>>(delta, DINNER, opw, DINNER,
                                                    h, DMODEL, nullptr,
                                                    MROWS, DMODEL, DINNER);
    }

    // fc -> out (3976 x 41)
    gemm_bt<1><<<dim3(32, 1), 256, 0, stream>>>(h, DMODEL, fc_w, DMODEL,
                                                out, NCLS, fc_b,
                                                MROWS, NCLS, DMODEL);
}

// Round 2
// 3245.560 us; speedup vs baseline: 1.2562x; 1.2562x over previous
//
#include <hip/hip_runtime.h>
#include <math.h>

#define NDIM    256
#define DMODEL  512
#define DSTATE  16
#define KLEN    14
#define DINNER  1024
#define DTRANK  32
#define BATCH   8
#define TLEN    2000
#define LOUT    497
#define MROWS   (BATCH*LOUT)   // 3976
#define NCLS    41
#define LAYERS  4

typedef __attribute__((ext_vector_type(8))) short short8;
typedef __attribute__((ext_vector_type(4))) float floatx4;

// ---------------- bf16 split helpers (RNE) ----------------
__device__ inline unsigned short bf16_rne(float f) {
    unsigned int u = __float_as_uint(f);
    u += 0x7fffu + ((u >> 16) & 1u);
    return (unsigned short)(u >> 16);
}
__device__ inline float bf16_to_f(unsigned short h) {
    return __uint_as_float(((unsigned int)h) << 16);
}
__device__ inline void write_hilo(float v, unsigned short* ph, unsigned short* pl) {
    unsigned short h = bf16_rne(v);
    *ph = h;
    *pl = bf16_rne(v - bf16_to_f(h));
}

// async global->LDS, 16B per lane; lds base must be wave-uniform
__device__ inline void gload16(const unsigned short* g, unsigned short* l) {
    __builtin_amdgcn_global_load_lds((const __attribute__((address_space(1))) void*)g,
                                     (__attribute__((address_space(3))) void*)l,
                                     16, 0, 0);
}

// ---------------------------------------------------------------------------
// Gaussian smoothing -> bf16 hi/lo (consumed only by day GEMM)
// ---------------------------------------------------------------------------
__global__ __launch_bounds__(256) void smooth_kernel(const float* __restrict__ X,
                                                     unsigned short* __restrict__ XSh,
                                                     unsigned short* __restrict__ XSl)
{
    __shared__ float w[20];
    int tid = threadIdx.x;
    if (tid < 20) {
        float t = ((float)tid - 9.5f) * 0.5f;
        w[tid] = expf(-0.5f * t * t);
    }
    __syncthreads();
    float s = 0.f;
    #pragma unroll
    for (int j = 0; j < 20; j++) s += w[j];
    float inv = 1.f / s;

    int idx = blockIdx.x * 256 + tid;
    if (idx >= BATCH * TLEN * NDIM) return;
    int d  = idx & 255;
    int bt = idx >> 8;
    int b  = bt / TLEN;
    int tt = bt - b * TLEN;
    const float* Xb = X + ((size_t)b * TLEN) * NDIM + d;
    float acc = 0.f;
    #pragma unroll
    for (int j = 0; j < 20; j++) {
        int t2 = tt - 9 + j;
        if (t2 >= 0 && t2 < TLEN) acc += Xb[(size_t)t2 * NDIM] * w[j];
    }
    write_hilo(acc * inv, XSh + idx, XSl + idx);
}

// ---------------------------------------------------------------------------
// Repack day weights for the 8 selected days: Wd[b][n][k] = day_w[day][k][n]
// hi/lo; also repack day bias into biasbuf[b*256+n].
// ---------------------------------------------------------------------------
__global__ __launch_bounds__(256) void repack_day(const float* __restrict__ day_w,
                                                  const float* __restrict__ day_b,
                                                  const int*   __restrict__ dayIdx,
                                                  unsigned short* __restrict__ Wh,
                                                  unsigned short* __restrict__ Wl,
                                                  float* __restrict__ biasbuf)
{
    int idx = blockIdx.x * 256 + threadIdx.x;   // 8*65536
    if (idx >= 8 * 65536) return;
    int b = idx >> 16;
    int rem = idx & 65535;
    int n = rem >> 8, k = rem & 255;
    int day = dayIdx[b];
    float v = day_w[(size_t)day * 65536 + (size_t)k * 256 + n];
    write_hilo(v, Wh + idx, Wl + idx);
    if (rem < 256) biasbuf[b * 256 + rem] = day_b[(size_t)day * 256 + rem];
}

// ---------------------------------------------------------------------------
// Repack lin_in_w with K reordered as kk' = r*256 + dd  (was kk = dd*14 + r)
// ---------------------------------------------------------------------------
__global__ __launch_bounds__(256) void repack_linin(const float* __restrict__ W,
                                                    unsigned short* __restrict__ Wh,
                                                    unsigned short* __restrict__ Wl)
{
    int idx = blockIdx.x * 256 + threadIdx.x;   // 512*3584
    if (idx >= 512 * 3584) return;
    int o = idx / 3584;
    int kk = idx - o * 3584;
    int r = kk >> 8, dd = kk & 255;
    float v = W[(size_t)o * 3584 + dd * 14 + r];
    write_hilo(v, Wh + idx, Wl + idx);
}

// ---------------------------------------------------------------------------
// Generic fp32 -> bf16 hi/lo conversion (weights)
// ---------------------------------------------------------------------------
__global__ __launch_bounds__(256) void convw_kernel(const float* __restrict__ src,
                                                    unsigned short* __restrict__ dh,
                                                    unsigned short* __restrict__ dl,
                                                    int n)
{
    int i = blockIdx.x * 256 + threadIdx.x;
    if (i < n) write_hilo(src[i], dh + i, dl + i);
}

// ---------------------------------------------------------------------------
// bf16x3 MFMA GEMM: C = A @ W^T  (A: MxK fp32 split hi/lo, W: NxK split hi/lo)
// 128x128 tile, 4 waves (2x2), BK=32, mfma_f32_16x16x32_bf16.
// Phases: Ah*Bh + Ah*Bl + Al*Bh.
// AMAP 0: A row m at Ah + m*lda
// AMAP 1: lin_in window gather: m=b*497+l -> base (b*2000+4l)*256, k contiguous
// AMAP 2: day: padded rows m in [0,16384), b=m>>11, t=m&2047 (<2000 valid),
//         B/bias offset by b, output row b*2000+t
// Epilogue: optional bias, ACT (1=softplus, 2=softsign), write fp32 and/or hi/lo.
// ---------------------------------------------------------------------------
template<int WF32, int WHL, int BIASF, int ACT, int AMAP>
__global__ __launch_bounds__(256) void mfma_gemm3(
    const unsigned short* __restrict__ Ah, const unsigned short* __restrict__ Al, int lda,
    const unsigned short* __restrict__ Bh, const unsigned short* __restrict__ Bl, int ldb,
    float* __restrict__ Cf, unsigned short* __restrict__ Ch, unsigned short* __restrict__ Cl,
    int ldc, const float* __restrict__ bias, int M, int N, int K)
{
    __shared__ __align__(16) unsigned short As[128 * 32];
    __shared__ __align__(16) unsigned short Bs[128 * 32];
    const int tid  = threadIdx.x;
    const int wave = tid >> 6, lane = tid & 63;
    const int wm = wave & 1, wn = wave >> 1;
    const int row0 = blockIdx.x * 128, col0 = blockIdx.y * 128;

    if (AMAP == 2) {
        int bb = row0 >> 11;
        Bh += (size_t)bb * 65536; Bl += (size_t)bb * 65536; bias += bb * 256;
    }

    // staging: 8 slots of (64 lanes x 16B); slots wave*2, wave*2+1 for A and B
    const int slot0 = wave * 2, slot1 = wave * 2 + 1;
    const int flat0 = slot0 * 64 + lane, flat1 = slot1 * 64 + lane;
    size_t abase0, abase1;
    {
        int r0 = row0 + (flat0 >> 2), r1 = row0 + (flat1 >> 2);
        int kc0 = (flat0 & 3) * 8,    kc1 = (flat1 & 3) * 8;
        if (AMAP == 0) {
            abase0 = (size_t)min(r0, M - 1) * lda + kc0;
            abase1 = (size_t)min(r1, M - 1) * lda + kc1;
        } else if (AMAP == 1) {
            int m0 = min(r0, M - 1), m1 = min(r1, M - 1);
            int b0 = m0 / 497, l0 = m0 - b0 * 497;
            int b1 = m1 / 497, l1 = m1 - b1 * 497;
            abase0 = ((size_t)(b0 * 2000 + l0 * 4) << 8) + kc0;
            abase1 = ((size_t)(b1 * 2000 + l1 * 4) << 8) + kc1;
        } else {
            int b0 = r0 >> 11, t0 = min(r0 & 2047, 1999);
            int b1 = r1 >> 11, t1 = min(r1 & 2047, 1999);
            abase0 = ((size_t)(b0 * 2000 + t0) << 8) + kc0;
            abase1 = ((size_t)(b1 * 2000 + t1) << 8) + kc1;
        }
    }
    size_t bbase0, bbase1;
    {
        int n0 = min(col0 + (flat0 >> 2), N - 1);
        int n1 = min(col0 + (flat1 >> 2), N - 1);
        bbase0 = (size_t)n0 * ldb + (flat0 & 3) * 8;
        bbase1 = (size_t)n1 * ldb + (flat1 & 3) * 8;
    }

    floatx4 acc[4][4];
    #pragma unroll
    for (int i = 0; i < 4; i++)
        #pragma unroll
        for (int j = 0; j < 4; j++) acc[i][j] = (floatx4){0.f, 0.f, 0.f, 0.f};

    const unsigned short* APh[3] = {Ah, Ah, Al};
    const unsigned short* BPh[3] = {Bh, Bl, Bh};
    const int mr = lane & 15, kq = (lane >> 4) * 8;

    for (int p = 0; p < 3; p++) {
        const unsigned short* Ap = APh[p];
        const unsigned short* Bp = BPh[p];
        for (int kt = 0; kt < K; kt += 32) {
            __syncthreads();
            gload16(Ap + abase0 + kt, &As[slot0 * 512]);
            gload16(Ap + abase1 + kt, &As[slot1 * 512]);
            gload16(Bp + bbase0 + kt, &Bs[slot0 * 512]);
            gload16(Bp + bbase1 + kt, &Bs[slot1 * 512]);
            __syncthreads();
            short8 af[4], bf[4];
            #pragma unroll
            for (int i = 0; i < 4; i++)
                af[i] = *(const short8*)&As[(wm * 64 + i * 16 + mr) * 32 + kq];
            #pragma unroll
            for (int j = 0; j < 4; j++)
                bf[j] = *(const short8*)&Bs[(wn * 64 + j * 16 + mr) * 32 + kq];
            #pragma unroll
            for (int i = 0; i < 4; i++)
                #pragma unroll
                for (int j = 0; j < 4; j++)
                    acc[i][j] = __builtin_amdgcn_mfma_f32_16x16x32_bf16(af[i], bf[j], acc[i][j], 0, 0, 0);
        }
    }

    const int rq = (lane >> 4) * 4;
    #pragma unroll
    for (int i = 0; i < 4; i++) {
        #pragma unroll
        for (int j = 0; j < 4; j++) {
            int colg = col0 + wn * 64 + j * 16 + mr;
            if (colg >= N) continue;
            #pragma unroll
            for (int r = 0; r < 4; r++) {
                int rowg = row0 + wm * 64 + i * 16 + rq + r;
                int orow; bool rok;
                if (AMAP == 2) {
                    int bb = rowg >> 11, t = rowg & 2047;
                    rok = (t < 2000);
                    orow = bb * 2000 + t;
                } else { rok = (rowg < M); orow = rowg; }
                if (!rok) continue;
                float v = acc[i][j][r];
                if (BIASF) v += bias[colg];
                if (ACT == 1) v = fmaxf(v, 0.f) + log1pf(expf(-fabsf(v)));
                if (ACT == 2) v = v / (1.f + fabsf(v));
                size_t oidx = (size_t)orow * ldc + colg;
                if (WF32) Cf[oidx] = v;
                if (WHL)  write_hilo(v, Ch + oidx, Cl + oidx);
            }
        }
    }
}

// ---------------------------------------------------------------------------
// Causal depthwise conv (k=4) + bias + SiLU; writes fp32 (scan) + hi/lo (x_proj A)
// ---------------------------------------------------------------------------
__global__ __launch_bounds__(256) void conv_silu_kernel(const float* __restrict__ XZ,
                                                        const float* __restrict__ cw,
                                                        const float* __restrict__ cb,
                                                        float* __restrict__ XC,
                                                        unsigned short* __restrict__ XCh,
                                                        unsigned short* __restrict__ XCl)
{
    int idx = blockIdx.x * 256 + threadIdx.x;   // 3976*1024
    if (idx >= MROWS * DINNER) return;
    int row = idx >> 10, c = idx & 1023;
    unsigned b = (unsigned)row / 497u;
    int l = row - (int)b * 497;
    float acc = cb[c];
    #pragma unroll
    for (int j = 0; j < 4; j++) {
        int lj = l - 3 + j;
        if (lj >= 0) acc += XZ[(size_t)(row - 3 + j) * 2048 + c] * cw[c * 4 + j];
    }
    float sig = 1.f / (1.f + expf(-acc));
    float v = acc * sig;
    XC[idx] = v;
    write_hilo(v, XCh + idx, XCl + idx);
}

// ---------------------------------------------------------------------------
// Selective scan; gating fused; writes y as bf16 hi/lo (out_proj A operand).
// ---------------------------------------------------------------------------
__global__ __launch_bounds__(256) void scan_kernel(const float* __restrict__ DELTA,
                                                   const float* __restrict__ XC,
                                                   const float* __restrict__ XZ,
                                                   const float* __restrict__ XDBC,
                                                   const float* __restrict__ Alog,
                                                   const float* __restrict__ Dp,
                                                   unsigned short* __restrict__ Yh,
                                                   unsigned short* __restrict__ Yl)
{
    __shared__ float sBC[32][32];
    int tid = threadIdx.x;
    int b = blockIdx.x >> 2;
    int d = (blockIdx.x & 3) * 256 + tid;
    int rowbase = b * LOUT;

    float a[DSTATE];
    #pragma unroll
    for (int n = 0; n < DSTATE; n++) a[n] = -expf(Alog[(size_t)d * DSTATE + n]);
    float dD = Dp[d];
    float s[DSTATE];
    #pragma unroll
    for (int n = 0; n < DSTATE; n++) s[n] = 0.f;

    int li = tid >> 3, lj = (tid & 7) * 4;

    for (int t0 = 0; t0 < LOUT; t0 += 32) {
        int tcnt = min(32, LOUT - t0);
        __syncthreads();
        if (li < tcnt) {
            float4 v = *(const float4*)(XDBC + (size_t)(rowbase + t0 + li) * 64 + 32 + lj);
            *(float4*)&sBC[li][lj] = v;
        }
        __syncthreads();
        for (int tt = 0; tt < tcnt; tt++) {
            size_t row = (size_t)(rowbase + t0 + tt);
            float dv = DELTA[row * DINNER + d];
            float xv = XC[row * DINNER + d];
            float zv = XZ[row * 2048 + DINNER + d];
            float dx = dv * xv;
            float y = 0.f;
            #pragma unroll
            for (int n = 0; n < DSTATE; n++) {
                float dA = expf(dv * a[n]);
                s[n] = fmaf(dA, s[n], dx * sBC[tt][n]);
                y = fmaf(s[n], sBC[tt][DSTATE + n], y);
            }
            float g = zv / (1.f + expf(-zv));
            float yv = (y + xv * dD) * g;
            write_hilo(yv, Yh + row * DINNER + d, Yl + row * DINNER + d);
        }
    }
}

// ---------------------------------------------------------------------------
extern "C" void kernel_launch(void* const* d_in, const int* in_sizes, int n_in,
                              void* d_out, int out_size, void* d_ws, size_t ws_size,
                              hipStream_t stream)
{
    const float* neuralInput = (const float*)d_in[0];
    const int*   dayIdx      = (const int*)  d_in[1];
    const float* day_w       = (const float*)d_in[2];
    const float* day_b       = (const float*)d_in[3];
    const float* lin_in_w    = (const float*)d_in[4];
    const float* lin_in_b    = (const float*)d_in[5];
    const float* in_proj_w   = (const float*)d_in[6];
    const float* conv_w      = (const float*)d_in[7];
    const float* conv_b      = (const float*)d_in[8];
    const float* x_proj_w    = (const float*)d_in[9];
    const float* dt_w        = (const float*)d_in[10];
    const float* dt_b        = (const float*)d_in[11];
    const float* A_log       = (const float*)d_in[12];
    const float* D_param     = (const float*)d_in[13];
    const float* out_proj_w  = (const float*)d_in[14];
    const float* fc_w        = (const float*)d_in[15];
    const float* fc_b        = (const float*)d_in[16];
    float* out = (float*)d_out;

    // ---------------- workspace layout (floats) ----------------
    float* p = (float*)d_ws;
    float* xz    = p; p += (size_t)MROWS * 2048;          // 8,142,848
    float* xconv = p; p += (size_t)MROWS * DINNER;        // 4,071,424
    float* delta = p; p += (size_t)MROWS * DINNER;        // 4,071,424
    float* xdbc  = p; p += (size_t)MROWS * 64;            //   254,464
    unsigned short* Hh = (unsigned short*)p;              // h hi/lo (3976x512)
    unsigned short* Hl = Hh + (size_t)MROWS * DMODEL;
    p += (size_t)MROWS * DMODEL;                          // 2,035,712 floats
    unsigned short* XSh = (unsigned short*)p;             // smooth out hi/lo (8x2000x256)
    unsigned short* XSl = XSh + (size_t)BATCH * TLEN * NDIM;
    p += (size_t)BATCH * TLEN * NDIM;                     // 4,096,000 floats
    unsigned short* XCh = XSh;                            // alias: conv out hi/lo (3976x1024)
    unsigned short* XCl = XCh + (size_t)MROWS * DINNER;
    unsigned short* XDh = (unsigned short*)p;             // day out hi/lo (8x2000x256)
    unsigned short* XDl = XDh + (size_t)BATCH * TLEN * NDIM;
    p += (size_t)BATCH * TLEN * NDIM;                     // 4,096,000 floats
    unsigned short* Yh = XDh;                             // alias: scan out hi/lo (3976x1024)
    unsigned short* Yl = Yh + (size_t)MROWS * DINNER;
    unsigned short* Dh = (unsigned short*)p;              // xdbc hi/lo (3976x64)
    unsigned short* Dl = Dh + (size_t)MROWS * 64;
    p += (size_t)MROWS * 64;                              //   254,464 floats
    unsigned short* Wh = (unsigned short*)p;              // weight scratch hi/lo
    unsigned short* Wl = Wh + 1835008;
    p += 1835008;                                         // 1,835,008 floats
    float* daybias = p; p += 2048;

    // 1. smooth -> XShl
    smooth_kernel<<<dim3((BATCH*TLEN*NDIM)/256), 256, 0, stream>>>(neuralInput, XSh, XSl);
    // 2. day weights repack + day GEMM (softsign) -> XDhl
    repack_day<<<dim3((8*65536)/256), 256, 0, stream>>>(day_w, day_b, dayIdx, Wh, Wl, daybias);
    mfma_gemm3<0,1,1,2,2><<<dim3(128, 2), 256, 0, stream>>>(
        XSh, XSl, 256, Wh, Wl, 256, nullptr, XDh, XDl, 256, daybias, 16000, 256, 256);
    // 3. lin_in repack + GEMM -> Hhl
    repack_linin<<<dim3((512*3584)/256), 256, 0, stream>>>(lin_in_w, Wh, Wl);
    mfma_gemm3<0,1,1,0,1><<<dim3(32, 4), 256, 0, stream>>>(
        XDh, XDl, 0, Wh, Wl, 3584, nullptr, Hh, Hl, DMODEL, lin_in_b, MROWS, DMODEL, 3584);

    for (int l = 0; l < LAYERS; l++) {
        const float* ipw = in_proj_w  + (size_t)l * 2048 * DMODEL;
        const float* cwl = conv_w     + (size_t)l * DINNER * 4;
        const float* cbl = conv_b     + (size_t)l * DINNER;
        const float* xpw = x_proj_w   + (size_t)l * 64 * DINNER;
        const float* dtw = dt_w       + (size_t)l * DINNER * DTRANK;
        const float* dtb = dt_b       + (size_t)l * DINNER;
        const float* alg = A_log      + (size_t)l * DINNER * DSTATE;
        const float* dpl = D_param    + (size_t)l * DINNER;
        const float* opw = out_proj_w + (size_t)l * DMODEL * DINNER;

        // in_proj: (3976x512)@(2048x512)^T -> xz fp32
        convw_kernel<<<dim3((2048*512)/256), 256, 0, stream>>>(ipw, Wh, Wl, 2048*512);
        mfma_gemm3<1,0,0,0,0><<<dim3(32, 16), 256, 0, stream>>>(
            Hh, Hl, DMODEL, Wh, Wl, DMODEL, xz, nullptr, nullptr, 2048, nullptr,
            MROWS, 2048, DMODEL);
        // conv + silu -> xconv fp32 + XChl
        conv_silu_kernel<<<dim3((MROWS*DINNER)/256), 256, 0, stream>>>(xz, cwl, cbl,
                                                                       xconv, XCh, XCl);
        // x_proj: (3976x1024)@(64x1024)^T -> xdbc fp32 + Dhl
        convw_kernel<<<dim3((64*1024)/256), 256, 0, stream>>>(xpw, Wh, Wl, 64*1024);
        mfma_gemm3<1,1,0,0,0><<<dim3(32, 1), 256, 0, stream>>>(
            XCh, XCl, DINNER, Wh, Wl, DINNER, xdbc, Dh, Dl, 64, nullptr,
            MROWS, 64, DINNER);
        // dt: (3976x32, lda=64)@(1024x32)^T + bias, softplus -> delta fp32
        convw_kernel<<<dim3((1024*32)/256), 256, 0, stream>>>(dtw, Wh, Wl, 1024*32);
        mfma_gemm3<1,0,1,1,0><<<dim3(32, 8), 256, 0, stream>>>(
            Dh, Dl, 64, Wh, Wl, DTRANK, delta, nullptr, nullptr, DINNER, dtb,
            MROWS, DINNER, DTRANK);
        // scan -> Yhl
        scan_kernel<<<dim3(32), 256, 0, stream>>>(delta, xconv, xz, xdbc, alg, dpl, Yh, Yl);
        // out_proj: (3976x1024)@(512x1024)^T -> Hhl
        convw_kernel<<<dim3((512*1024)/256), 256, 0, stream>>>(opw, Wh, Wl, 512*1024);
        mfma_gemm3<0,1,0,0,0><<<dim3(32, 4), 256, 0, stream>>>(
            Yh, Yl, DINNER, Wh, Wl, DINNER, nullptr, Hh, Hl, DMODEL, nullptr,
            MROWS, DMODEL, DINNER);
    }

    // fc -> out (3976 x 41), fp32 + bias
    convw_kernel<<<dim3((NCLS*DMODEL+255)/256), 256, 0, stream>>>(fc_w, Wh, Wl, NCLS*DMODEL);
    mfma_gemm3<1,0,1,0,0><<<dim3(32, 1), 256, 0, stream>>>(
        Hh, Hl, DMODEL, Wh, Wl, DMODEL, out, nullptr, nullptr, NCLS, fc_b,
        MROWS, NCLS, DMODEL);
}

// Round 3
// 2208.058 us; speedup vs baseline: 1.8465x; 1.4699x over previous
//
#include <hip/hip_runtime.h>
#include <math.h>

#define NDIM    256
#define DMODEL  512
#define DSTATE  16
#define KLEN    14
#define DINNER  1024
#define DTRANK  32
#define BATCH   8
#define TLEN    2000
#define LOUT    497
#define MROWS   (BATCH*LOUT)   // 3976
#define NCLS    41
#define LAYERS  4
#define NCH     13
#define CSZ     39

typedef __attribute__((ext_vector_type(8))) short short8;
typedef __attribute__((ext_vector_type(4))) float floatx4;

// ---------------- bf16 split helpers (RNE) ----------------
__device__ inline unsigned short bf16_rne(float f) {
    unsigned int u = __float_as_uint(f);
    u += 0x7fffu + ((u >> 16) & 1u);
    return (unsigned short)(u >> 16);
}
__device__ inline float bf16_to_f(unsigned short h) {
    return __uint_as_float(((unsigned int)h) << 16);
}
__device__ inline void write_hilo(float v, unsigned short* ph, unsigned short* pl) {
    unsigned short h = bf16_rne(v);
    *ph = h;
    *pl = bf16_rne(v - bf16_to_f(h));
}

// async global->LDS, 16B per lane; lds base must be wave-uniform
__device__ inline void gload16(const unsigned short* g, unsigned short* l) {
    __builtin_amdgcn_global_load_lds((const __attribute__((address_space(1))) void*)g,
                                     (__attribute__((address_space(3))) void*)l,
                                     16, 0, 0);
}

// ---------------------------------------------------------------------------
// Gaussian smoothing -> bf16 hi/lo (consumed only by day GEMM)
// ---------------------------------------------------------------------------
__global__ __launch_bounds__(256) void smooth_kernel(const float* __restrict__ X,
                                                     unsigned short* __restrict__ XSh,
                                                     unsigned short* __restrict__ XSl)
{
    __shared__ float w[20];
    int tid = threadIdx.x;
    if (tid < 20) {
        float t = ((float)tid - 9.5f) * 0.5f;
        w[tid] = expf(-0.5f * t * t);
    }
    __syncthreads();
    float s = 0.f;
    #pragma unroll
    for (int j = 0; j < 20; j++) s += w[j];
    float inv = 1.f / s;

    int idx = blockIdx.x * 256 + tid;
    if (idx >= BATCH * TLEN * NDIM) return;
    int d  = idx & 255;
    int bt = idx >> 8;
    int b  = bt / TLEN;
    int tt = bt - b * TLEN;
    const float* Xb = X + ((size_t)b * TLEN) * NDIM + d;
    float acc = 0.f;
    #pragma unroll
    for (int j = 0; j < 20; j++) {
        int t2 = tt - 9 + j;
        if (t2 >= 0 && t2 < TLEN) acc += Xb[(size_t)t2 * NDIM] * w[j];
    }
    write_hilo(acc * inv, XSh + idx, XSl + idx);
}

// ---------------------------------------------------------------------------
// Repack day weights for the 8 selected days (transposed, hi/lo) + bias
// ---------------------------------------------------------------------------
__global__ __launch_bounds__(256) void repack_day(const float* __restrict__ day_w,
                                                  const float* __restrict__ day_b,
                                                  const int*   __restrict__ dayIdx,
                                                  unsigned short* __restrict__ Wh,
                                                  unsigned short* __restrict__ Wl,
                                                  float* __restrict__ biasbuf)
{
    int idx = blockIdx.x * 256 + threadIdx.x;   // 8*65536
    if (idx >= 8 * 65536) return;
    int b = idx >> 16;
    int rem = idx & 65535;
    int n = rem >> 8, k = rem & 255;
    int day = dayIdx[b];
    float v = day_w[(size_t)day * 65536 + (size_t)k * 256 + n];
    write_hilo(v, Wh + idx, Wl + idx);
    if (rem < 256) biasbuf[b * 256 + rem] = day_b[(size_t)day * 256 + rem];
}

// ---------------------------------------------------------------------------
// Repack lin_in_w with K reordered as kk' = r*256 + dd  (was kk = dd*14 + r)
// ---------------------------------------------------------------------------
__global__ __launch_bounds__(256) void repack_linin(const float* __restrict__ W,
                                                    unsigned short* __restrict__ Wh,
                                                    unsigned short* __restrict__ Wl)
{
    int idx = blockIdx.x * 256 + threadIdx.x;   // 512*3584
    if (idx >= 512 * 3584) return;
    int o = idx / 3584;
    int kk = idx - o * 3584;
    int r = kk >> 8, dd = kk & 255;
    float v = W[(size_t)o * 3584 + dd * 14 + r];
    write_hilo(v, Wh + idx, Wl + idx);
}

// ---------------------------------------------------------------------------
// Generic fp32 -> bf16 hi/lo conversion (weights)
// ---------------------------------------------------------------------------
__global__ __launch_bounds__(256) void convw_kernel(const float* __restrict__ src,
                                                    unsigned short* __restrict__ dh,
                                                    unsigned short* __restrict__ dl,
                                                    int n)
{
    int i = blockIdx.x * 256 + threadIdx.x;
    if (i < n) write_hilo(src[i], dh + i, dl + i);
}

// ---------------------------------------------------------------------------
// bf16x3 MFMA GEMM: C = A @ W^T (hi/lo split operands), 128x128 tile, BK=32
// ---------------------------------------------------------------------------
template<int WF32, int WHL, int BIASF, int ACT, int AMAP>
__global__ __launch_bounds__(256) void mfma_gemm3(
    const unsigned short* __restrict__ Ah, const unsigned short* __restrict__ Al, int lda,
    const unsigned short* __restrict__ Bh, const unsigned short* __restrict__ Bl, int ldb,
    float* __restrict__ Cf, unsigned short* __restrict__ Ch, unsigned short* __restrict__ Cl,
    int ldc, const float* __restrict__ bias, int M, int N, int K)
{
    __shared__ __align__(16) unsigned short As[128 * 32];
    __shared__ __align__(16) unsigned short Bs[128 * 32];
    const int tid  = threadIdx.x;
    const int wave = tid >> 6, lane = tid & 63;
    const int wm = wave & 1, wn = wave >> 1;
    const int row0 = blockIdx.x * 128, col0 = blockIdx.y * 128;

    if (AMAP == 2) {
        int bb = row0 >> 11;
        Bh += (size_t)bb * 65536; Bl += (size_t)bb * 65536; bias += bb * 256;
    }

    const int slot0 = wave * 2, slot1 = wave * 2 + 1;
    const int flat0 = slot0 * 64 + lane, flat1 = slot1 * 64 + lane;
    size_t abase0, abase1;
    {
        int r0 = row0 + (flat0 >> 2), r1 = row0 + (flat1 >> 2);
        int kc0 = (flat0 & 3) * 8,    kc1 = (flat1 & 3) * 8;
        if (AMAP == 0) {
            abase0 = (size_t)min(r0, M - 1) * lda + kc0;
            abase1 = (size_t)min(r1, M - 1) * lda + kc1;
        } else if (AMAP == 1) {
            int m0 = min(r0, M - 1), m1 = min(r1, M - 1);
            int b0 = m0 / 497, l0 = m0 - b0 * 497;
            int b1 = m1 / 497, l1 = m1 - b1 * 497;
            abase0 = ((size_t)(b0 * 2000 + l0 * 4) << 8) + kc0;
            abase1 = ((size_t)(b1 * 2000 + l1 * 4) << 8) + kc1;
        } else {
            int b0 = r0 >> 11, t0 = min(r0 & 2047, 1999);
            int b1 = r1 >> 11, t1 = min(r1 & 2047, 1999);
            abase0 = ((size_t)(b0 * 2000 + t0) << 8) + kc0;
            abase1 = ((size_t)(b1 * 2000 + t1) << 8) + kc1;
        }
    }
    size_t bbase0, bbase1;
    {
        int n0 = min(col0 + (flat0 >> 2), N - 1);
        int n1 = min(col0 + (flat1 >> 2), N - 1);
        bbase0 = (size_t)n0 * ldb + (flat0 & 3) * 8;
        bbase1 = (size_t)n1 * ldb + (flat1 & 3) * 8;
    }

    floatx4 acc[4][4];
    #pragma unroll
    for (int i = 0; i < 4; i++)
        #pragma unroll
        for (int j = 0; j < 4; j++) acc[i][j] = (floatx4){0.f, 0.f, 0.f, 0.f};

    const unsigned short* APh[3] = {Ah, Ah, Al};
    const unsigned short* BPh[3] = {Bh, Bl, Bh};
    const int mr = lane & 15, kq = (lane >> 4) * 8;

    for (int p = 0; p < 3; p++) {
        const unsigned short* Ap = APh[p];
        const unsigned short* Bp = BPh[p];
        for (int kt = 0; kt < K; kt += 32) {
            __syncthreads();
            gload16(Ap + abase0 + kt, &As[slot0 * 512]);
            gload16(Ap + abase1 + kt, &As[slot1 * 512]);
            gload16(Bp + bbase0 + kt, &Bs[slot0 * 512]);
            gload16(Bp + bbase1 + kt, &Bs[slot1 * 512]);
            __syncthreads();
            short8 af[4], bf[4];
            #pragma unroll
            for (int i = 0; i < 4; i++)
                af[i] = *(const short8*)&As[(wm * 64 + i * 16 + mr) * 32 + kq];
            #pragma unroll
            for (int j = 0; j < 4; j++)
                bf[j] = *(const short8*)&Bs[(wn * 64 + j * 16 + mr) * 32 + kq];
            #pragma unroll
            for (int i = 0; i < 4; i++)
                #pragma unroll
                for (int j = 0; j < 4; j++)
                    acc[i][j] = __builtin_amdgcn_mfma_f32_16x16x32_bf16(af[i], bf[j], acc[i][j], 0, 0, 0);
        }
    }

    const int rq = (lane >> 4) * 4;
    #pragma unroll
    for (int i = 0; i < 4; i++) {
        #pragma unroll
        for (int j = 0; j < 4; j++) {
            int colg = col0 + wn * 64 + j * 16 + mr;
            if (colg >= N) continue;
            #pragma unroll
            for (int r = 0; r < 4; r++) {
                int rowg = row0 + wm * 64 + i * 16 + rq + r;
                int orow; bool rok;
                if (AMAP == 2) {
                    int bb = rowg >> 11, t = rowg & 2047;
                    rok = (t < 2000);
                    orow = bb * 2000 + t;
                } else { rok = (rowg < M); orow = rowg; }
                if (!rok) continue;
                float v = acc[i][j][r];
                if (BIASF) v += bias[colg];
                if (ACT == 1) v = fmaxf(v, 0.f) + log1pf(expf(-fabsf(v)));
                if (ACT == 2) v = v / (1.f + fabsf(v));
                size_t oidx = (size_t)orow * ldc + colg;
                if (WF32) Cf[oidx] = v;
                if (WHL)  write_hilo(v, Ch + oidx, Cl + oidx);
            }
        }
    }
}

// ---------------------------------------------------------------------------
// Causal depthwise conv (k=4) + bias + SiLU; writes fp32 (scan) + hi/lo (x_proj A)
// ---------------------------------------------------------------------------
__global__ __launch_bounds__(256) void conv_silu_kernel(const float* __restrict__ XZ,
                                                        const float* __restrict__ cw,
                                                        const float* __restrict__ cb,
                                                        float* __restrict__ XC,
                                                        unsigned short* __restrict__ XCh,
                                                        unsigned short* __restrict__ XCl)
{
    int idx = blockIdx.x * 256 + threadIdx.x;   // 3976*1024
    if (idx >= MROWS * DINNER) return;
    int row = idx >> 10, c = idx & 1023;
    unsigned b = (unsigned)row / 497u;
    int l = row - (int)b * 497;
    float acc = cb[c];
    #pragma unroll
    for (int j = 0; j < 4; j++) {
        int lj = l - 3 + j;
        if (lj >= 0) acc += XZ[(size_t)(row - 3 + j) * 2048 + c] * cw[c * 4 + j];
    }
    float sig = 1.f / (1.f + expf(-acc));
    float v = acc * sig;
    XC[idx] = v;
    write_hilo(v, XCh + idx, XCl + idx);
}

// ---------------------------------------------------------------------------
// Chunked scan, phase 1: per (b,d,chunk) local scan from 0 + decay product
// ---------------------------------------------------------------------------
__global__ __launch_bounds__(256) void scan_part1(const float* __restrict__ DELTA,
                                                  const float* __restrict__ XC,
                                                  const float* __restrict__ XDBC,
                                                  const float* __restrict__ Alog,
                                                  float* __restrict__ SEnd,
                                                  float* __restrict__ Pp)
{
    __shared__ float sB[CSZ][16];
    int tid = threadIdx.x;
    int bid = blockIdx.x;
    int c = bid % NCH; int r = bid / NCH;
    int db = r & 3, b = r >> 2;
    int d = db * 256 + tid;
    int t0 = c * CSZ;
    int tcnt = min(CSZ, LOUT - t0);
    int rowbase = b * LOUT + t0;

    int li = tid >> 2, lj = (tid & 3) * 4;
    if (li < tcnt)
        *(float4*)&sB[li][lj] = *(const float4*)(XDBC + (size_t)(rowbase + li) * 64 + 32 + lj);
    __syncthreads();

    float a[DSTATE], cum[DSTATE], s[DSTATE];
    #pragma unroll
    for (int n = 0; n < DSTATE; n++) {
        a[n] = -expf(Alog[(size_t)d * DSTATE + n]);
        cum[n] = 1.f; s[n] = 0.f;
    }
    for (int tt = 0; tt < tcnt; tt++) {
        size_t row = (size_t)(rowbase + tt);
        float dv = DELTA[row * DINNER + d];
        float xv = XC[row * DINNER + d];
        float dx = dv * xv;
        #pragma unroll
        for (int n = 0; n < DSTATE; n++) {
            float e = expf(dv * a[n]);
            cum[n] *= e;
            s[n] = fmaf(e, s[n], dx * sB[tt][n]);
        }
    }
    size_t base = ((size_t)(c * 8 + b) * 16) * 1024 + d;
    #pragma unroll
    for (int n = 0; n < DSTATE; n++) {
        SEnd[base + (size_t)n * 1024] = s[n];
        Pp[base + (size_t)n * 1024]   = cum[n];
    }
}

// ---------------------------------------------------------------------------
// Chunked scan, phase 2: combine chunk summaries -> per-chunk incoming state
// ---------------------------------------------------------------------------
__global__ __launch_bounds__(256) void scan_part2(const float* __restrict__ SEnd,
                                                  const float* __restrict__ Pp,
                                                  float* __restrict__ SIn)
{
    int tid = threadIdx.x;
    int bid = blockIdx.x;           // 512 = 8b * 16n * 4db
    int db = bid & 3, n = (bid >> 2) & 15, b = bid >> 6;
    int d = db * 256 + tid;
    float s = 0.f;
    for (int c = 0; c < NCH; c++) {
        size_t idx = ((size_t)(c * 8 + b) * 16 + n) * 1024 + d;
        SIn[idx] = s;
        s = fmaf(Pp[idx], s, SEnd[idx]);
    }
}

// ---------------------------------------------------------------------------
// Chunked scan, phase 3: recompute with true incoming state, emit gated y
// ---------------------------------------------------------------------------
__global__ __launch_bounds__(256) void scan_part3(const float* __restrict__ DELTA,
                                                  const float* __restrict__ XC,
                                                  const float* __restrict__ XZ,
                                                  const float* __restrict__ XDBC,
                                                  const float* __restrict__ Alog,
                                                  const float* __restrict__ Dp,
                                                  const float* __restrict__ SIn,
                                                  unsigned short* __restrict__ Yh,
                                                  unsigned short* __restrict__ Yl)
{
    __shared__ float sBC[CSZ][32];
    int tid = threadIdx.x;
    int bid = blockIdx.x;
    int c = bid % NCH; int r = bid / NCH;
    int db = r & 3, b = r >> 2;
    int d = db * 256 + tid;
    int t0 = c * CSZ;
    int tcnt = min(CSZ, LOUT - t0);
    int rowbase = b * LOUT + t0;

    int li = tid >> 3, lj = (tid & 7) * 4;
    if (li < tcnt)
        *(float4*)&sBC[li][lj] = *(const float4*)(XDBC + (size_t)(rowbase + li) * 64 + 32 + lj);
    int li2 = li + 32;
    if (li2 < tcnt)
        *(float4*)&sBC[li2][lj] = *(const float4*)(XDBC + (size_t)(rowbase + li2) * 64 + 32 + lj);
    __syncthreads();

    float a[DSTATE], s[DSTATE];
    size_t base = ((size_t)(c * 8 + b) * 16) * 1024 + d;
    #pragma unroll
    for (int n = 0; n < DSTATE; n++) {
        a[n] = -expf(Alog[(size_t)d * DSTATE + n]);
        s[n] = SIn[base + (size_t)n * 1024];
    }
    float dD = Dp[d];

    for (int tt = 0; tt < tcnt; tt++) {
        size_t row = (size_t)(rowbase + tt);
        float dv = DELTA[row * DINNER + d];
        float xv = XC[row * DINNER + d];
        float zv = XZ[row * 2048 + DINNER + d];
        float dx = dv * xv;
        float y = 0.f;
        #pragma unroll
        for (int n = 0; n < DSTATE; n++) {
            float e = expf(dv * a[n]);
            s[n] = fmaf(e, s[n], dx * sBC[tt][n]);
            y = fmaf(s[n], sBC[tt][DSTATE + n], y);
        }
        float g = zv / (1.f + expf(-zv));
        float yv = (y + xv * dD) * g;
        write_hilo(yv, Yh + row * DINNER + d, Yl + row * DINNER + d);
    }
}

// ---------------------------------------------------------------------------
extern "C" void kernel_launch(void* const* d_in, const int* in_sizes, int n_in,
                              void* d_out, int out_size, void* d_ws, size_t ws_size,
                              hipStream_t stream)
{
    const float* neuralInput = (const float*)d_in[0];
    const int*   dayIdx      = (const int*)  d_in[1];
    const float* day_w       = (const float*)d_in[2];
    const float* day_b       = (const float*)d_in[3];
    const float* lin_in_w    = (const float*)d_in[4];
    const float* lin_in_b    = (const float*)d_in[5];
    const float* in_proj_w   = (const float*)d_in[6];
    const float* conv_w      = (const float*)d_in[7];
    const float* conv_b      = (const float*)d_in[8];
    const float* x_proj_w    = (const float*)d_in[9];
    const float* dt_w        = (const float*)d_in[10];
    const float* dt_b        = (const float*)d_in[11];
    const float* A_log       = (const float*)d_in[12];
    const float* D_param     = (const float*)d_in[13];
    const float* out_proj_w  = (const float*)d_in[14];
    const float* fc_w        = (const float*)d_in[15];
    const float* fc_b        = (const float*)d_in[16];
    float* out = (float*)d_out;

    // ---------------- workspace layout (floats) ----------------
    float* p = (float*)d_ws;
    float* xz    = p; p += (size_t)MROWS * 2048;          // 8,142,848
    float* xconv = p; p += (size_t)MROWS * DINNER;        // 4,071,424
    float* delta = p; p += (size_t)MROWS * DINNER;        // 4,071,424
    float* xdbc  = p; p += (size_t)MROWS * 64;            //   254,464
    unsigned short* Hh = (unsigned short*)p;              // h hi/lo (3976x512)
    unsigned short* Hl = Hh + (size_t)MROWS * DMODEL;
    p += (size_t)MROWS * DMODEL;                          // 2,035,712 floats
    unsigned short* XSh = (unsigned short*)p;             // smooth out hi/lo
    unsigned short* XSl = XSh + (size_t)BATCH * TLEN * NDIM;
    p += (size_t)BATCH * TLEN * NDIM;                     // 4,096,000 floats
    unsigned short* XCh = XSh;                            // alias: conv out hi/lo
    unsigned short* XCl = XCh + (size_t)MROWS * DINNER;
    float* xdreg = p;                                     // day-out region (4,096,000 floats)
    unsigned short* XDh = (unsigned short*)p;
    unsigned short* XDl = XDh + (size_t)BATCH * TLEN * NDIM;
    p += (size_t)BATCH * TLEN * NDIM;
    unsigned short* Yh = XDh;                             // alias: scan out hi/lo
    unsigned short* Yl = Yh + (size_t)MROWS * DINNER;
    float* SEnd = xdreg;                                  // alias (dead before phase C)
    float* Pp   = SEnd + (size_t)NCH * 8 * 16 * 1024;     // 1,703,936 each; 3.41M <= 4.096M
    unsigned short* Dh = (unsigned short*)p;              // xdbc hi/lo (3976x64)
    unsigned short* Dl = Dh + (size_t)MROWS * 64;
    p += (size_t)MROWS * 64;                              //   254,464 floats
    unsigned short* Wh = (unsigned short*)p;              // weight scratch hi/lo
    unsigned short* Wl = Wh + 1835008;
    float* SIn = (float*)Wh;                              // alias (1,703,936 <= 1,835,008)
    p += 1835008;                                         // 1,835,008 floats
    float* daybias = p; p += 2048;

    // 1. smooth -> XShl
    smooth_kernel<<<dim3((BATCH*TLEN*NDIM)/256), 256, 0, stream>>>(neuralInput, XSh, XSl);
    // 2. day weights repack + day GEMM (softsign) -> XDhl
    repack_day<<<dim3((8*65536)/256), 256, 0, stream>>>(day_w, day_b, dayIdx, Wh, Wl, daybias);
    mfma_gemm3<0,1,1,2,2><<<dim3(128, 2), 256, 0, stream>>>(
        XSh, XSl, 256, Wh, Wl, 256, nullptr, XDh, XDl, 256, daybias, 16000, 256, 256);
    // 3. lin_in repack + GEMM -> Hhl
    repack_linin<<<dim3((512*3584)/256), 256, 0, stream>>>(lin_in_w, Wh, Wl);
    mfma_gemm3<0,1,1,0,1><<<dim3(32, 4), 256, 0, stream>>>(
        XDh, XDl, 0, Wh, Wl, 3584, nullptr, Hh, Hl, DMODEL, lin_in_b, MROWS, DMODEL, 3584);

    for (int l = 0; l < LAYERS; l++) {
        const float* ipw = in_proj_w  + (size_t)l * 2048 * DMODEL;
        const float* cwl = conv_w     + (size_t)l * DINNER * 4;
        const float* cbl = conv_b     + (size_t)l * DINNER;
        const float* xpw = x_proj_w   + (size_t)l * 64 * DINNER;
        const float* dtw = dt_w       + (size_t)l * DINNER * DTRANK;
        const float* dtb = dt_b       + (size_t)l * DINNER;
        const float* alg = A_log      + (size_t)l * DINNER * DSTATE;
        const float* dpl = D_param    + (size_t)l * DINNER;
        const float* opw = out_proj_w + (size_t)l * DMODEL * DINNER;

        // in_proj: (3976x512)@(2048x512)^T -> xz fp32
        convw_kernel<<<dim3((2048*512)/256), 256, 0, stream>>>(ipw, Wh, Wl, 2048*512);
        mfma_gemm3<1,0,0,0,0><<<dim3(32, 16), 256, 0, stream>>>(
            Hh, Hl, DMODEL, Wh, Wl, DMODEL, xz, nullptr, nullptr, 2048, nullptr,
            MROWS, 2048, DMODEL);
        // conv + silu -> xconv fp32 + XChl
        conv_silu_kernel<<<dim3((MROWS*DINNER)/256), 256, 0, stream>>>(xz, cwl, cbl,
                                                                       xconv, XCh, XCl);
        // x_proj: (3976x1024)@(64x1024)^T -> xdbc fp32 + Dhl
        convw_kernel<<<dim3((64*1024)/256), 256, 0, stream>>>(xpw, Wh, Wl, 64*1024);
        mfma_gemm3<1,1,0,0,0><<<dim3(32, 1), 256, 0, stream>>>(
            XCh, XCl, DINNER, Wh, Wl, DINNER, xdbc, Dh, Dl, 64, nullptr,
            MROWS, 64, DINNER);
        // dt: (3976x32, lda=64)@(1024x32)^T + bias, softplus -> delta fp32
        convw_kernel<<<dim3((1024*32)/256), 256, 0, stream>>>(dtw, Wh, Wl, 1024*32);
        mfma_gemm3<1,0,1,1,0><<<dim3(32, 8), 256, 0, stream>>>(
            Dh, Dl, 64, Wh, Wl, DTRANK, delta, nullptr, nullptr, DINNER, dtb,
            MROWS, DINNER, DTRANK);
        // chunked scan: A (local scans) -> B (combine) -> C (recompute + gate) -> Yhl
        scan_part1<<<dim3(8*4*NCH), 256, 0, stream>>>(delta, xconv, xdbc, alg, SEnd, Pp);
        scan_part2<<<dim3(512), 256, 0, stream>>>(SEnd, Pp, SIn);
        scan_part3<<<dim3(8*4*NCH), 256, 0, stream>>>(delta, xconv, xz, xdbc, alg, dpl,
                                                      SIn, Yh, Yl);
        // out_proj: (3976x1024)@(512x1024)^T -> Hhl
        convw_kernel<<<dim3((512*1024)/256), 256, 0, stream>>>(opw, Wh, Wl, 512*1024);
        mfma_gemm3<0,1,0,0,0><<<dim3(32, 4), 256, 0, stream>>>(
            Yh, Yl, DINNER, Wh, Wl, DINNER, nullptr, Hh, Hl, DMODEL, nullptr,
            MROWS, DMODEL, DINNER);
    }

    // fc -> out (3976 x 41), fp32 + bias
    convw_kernel<<<dim3((NCLS*DMODEL+255)/256), 256, 0, stream>>>(fc_w, Wh, Wl, NCLS*DMODEL);
    mfma_gemm3<1,0,1,0,0><<<dim3(32, 1), 256, 0, stream>>>(
        Hh, Hl, DMODEL, Wh, Wl, DMODEL, out, nullptr, nullptr, NCLS, fc_b,
        MROWS, NCLS, DMODEL);
}

// Round 4
// 1256.238 us; speedup vs baseline: 3.2455x; 1.7577x over previous
//
#include <hip/hip_runtime.h>
#include <math.h>

#define NDIM    256
#define DMODEL  512
#define DSTATE  16
#define KLEN    14
#define DINNER  1024
#define DTRANK  32
#define BATCH   8
#define TLEN    2000
#define LOUT    497
#define MROWS   (BATCH*LOUT)   // 3976
#define NCLS    41
#define LAYERS  4
#define NCH     13
#define CSZ     39

typedef __attribute__((ext_vector_type(8))) short short8;
typedef __attribute__((ext_vector_type(4))) float floatx4;

// ---------------- bf16 split helpers (RNE) ----------------
__device__ inline unsigned short bf16_rne(float f) {
    unsigned int u = __float_as_uint(f);
    u += 0x7fffu + ((u >> 16) & 1u);
    return (unsigned short)(u >> 16);
}
__device__ inline float bf16_to_f(unsigned short h) {
    return __uint_as_float(((unsigned int)h) << 16);
}
__device__ inline void write_hilo(float v, unsigned short* ph, unsigned short* pl) {
    unsigned short h = bf16_rne(v);
    *ph = h;
    *pl = bf16_rne(v - bf16_to_f(h));
}

__device__ inline void gload16(const unsigned short* g, unsigned short* l) {
    __builtin_amdgcn_global_load_lds((const __attribute__((address_space(1))) void*)g,
                                     (__attribute__((address_space(3))) void*)l,
                                     16, 0, 0);
}

// ---------------------------------------------------------------------------
// Gaussian smoothing -> bf16 hi/lo
// ---------------------------------------------------------------------------
__global__ __launch_bounds__(256) void smooth_kernel(const float* __restrict__ X,
                                                     unsigned short* __restrict__ XSh,
                                                     unsigned short* __restrict__ XSl)
{
    __shared__ float w[20];
    int tid = threadIdx.x;
    if (tid < 20) {
        float t = ((float)tid - 9.5f) * 0.5f;
        w[tid] = expf(-0.5f * t * t);
    }
    __syncthreads();
    float s = 0.f;
    #pragma unroll
    for (int j = 0; j < 20; j++) s += w[j];
    float inv = 1.f / s;

    int idx = blockIdx.x * 256 + tid;
    if (idx >= BATCH * TLEN * NDIM) return;
    int d  = idx & 255;
    int bt = idx >> 8;
    int b  = bt / TLEN;
    int tt = bt - b * TLEN;
    const float* Xb = X + ((size_t)b * TLEN) * NDIM + d;
    float acc = 0.f;
    #pragma unroll
    for (int j = 0; j < 20; j++) {
        int t2 = tt - 9 + j;
        if (t2 >= 0 && t2 < TLEN) acc += Xb[(size_t)t2 * NDIM] * w[j];
    }
    write_hilo(acc * inv, XSh + idx, XSl + idx);
}

// ---------------------------------------------------------------------------
// Repack day weights for the 8 selected days (transposed, hi/lo) + bias
// ---------------------------------------------------------------------------
__global__ __launch_bounds__(256) void repack_day(const float* __restrict__ day_w,
                                                  const float* __restrict__ day_b,
                                                  const int*   __restrict__ dayIdx,
                                                  unsigned short* __restrict__ Wh,
                                                  unsigned short* __restrict__ Wl,
                                                  float* __restrict__ biasbuf)
{
    int idx = blockIdx.x * 256 + threadIdx.x;   // 8*65536
    if (idx >= 8 * 65536) return;
    int b = idx >> 16;
    int rem = idx & 65535;
    int n = rem >> 8, k = rem & 255;
    int day = dayIdx[b];
    float v = day_w[(size_t)day * 65536 + (size_t)k * 256 + n];
    write_hilo(v, Wh + idx, Wl + idx);
    if (rem < 256) biasbuf[b * 256 + rem] = day_b[(size_t)day * 256 + rem];
}

// ---------------------------------------------------------------------------
// Repack lin_in_w with K reordered as kk' = r*256 + dd
// ---------------------------------------------------------------------------
__global__ __launch_bounds__(256) void repack_linin(const float* __restrict__ W,
                                                    unsigned short* __restrict__ Wh,
                                                    unsigned short* __restrict__ Wl)
{
    int idx = blockIdx.x * 256 + threadIdx.x;   // 512*3584
    if (idx >= 512 * 3584) return;
    int o = idx / 3584;
    int kk = idx - o * 3584;
    int r = kk >> 8, dd = kk & 255;
    float v = W[(size_t)o * 3584 + dd * 14 + r];
    write_hilo(v, Wh + idx, Wl + idx);
}

// ---------------------------------------------------------------------------
// Generic fp32 -> bf16 hi/lo conversion (weights)
// ---------------------------------------------------------------------------
__global__ __launch_bounds__(256) void convw_kernel(const float* __restrict__ src,
                                                    unsigned short* __restrict__ dh,
                                                    unsigned short* __restrict__ dl,
                                                    int n)
{
    int i = blockIdx.x * 256 + threadIdx.x;
    if (i < n) write_hilo(src[i], dh + i, dl + i);
}

// ---------------------------------------------------------------------------
// Fused bf16x3 MFMA GEMM: single K-pass, 4 LDS tiles (Ah/Al/Bh/Bl), 48 MFMA
// per BK=32 step. 128x128 tile, 4 waves. Source-side LDS swizzle (group ^ row&3).
// SPLIT: blockIdx.z = K-split id; raw fp32 partials to Cf + z*M*ldc.
// ---------------------------------------------------------------------------
template<int WF32, int WHL, int BIASF, int ACT, int AMAP, int SPLIT>
__global__ __launch_bounds__(256) void mfma_gemm3(
    const unsigned short* __restrict__ Ah, const unsigned short* __restrict__ Al, int lda,
    const unsigned short* __restrict__ Bh, const unsigned short* __restrict__ Bl, int ldb,
    float* __restrict__ Cf, unsigned short* __restrict__ Ch, unsigned short* __restrict__ Cl,
    int ldc, const float* __restrict__ bias, int M, int N, int K, int Kc)
{
    __shared__ __align__(16) unsigned short AsH[4096];
    __shared__ __align__(16) unsigned short AsL[4096];
    __shared__ __align__(16) unsigned short BsH[4096];
    __shared__ __align__(16) unsigned short BsL[4096];
    const int tid  = threadIdx.x;
    const int wave = tid >> 6, lane = tid & 63;
    const int wm = wave & 1, wn = wave >> 1;
    const int row0 = blockIdx.x * 128, col0 = blockIdx.y * 128;

    if (AMAP == 2) {
        int bb = row0 >> 11;
        Bh += (size_t)bb * 65536; Bl += (size_t)bb * 65536; bias += bb * 256;
    }

    int k0 = 0, kend = K;
    if (SPLIT) {
        k0 = blockIdx.z * Kc;
        kend = min(K, k0 + Kc);
        Cf += (size_t)blockIdx.z * (size_t)M * ldc;
    }

    // staging: per wave 2 slots (64 lanes x 16B each) per tile
    const int slot0 = wave * 2, slot1 = wave * 2 + 1;
    const int f0 = slot0 * 64 + lane, f1 = slot1 * 64 + lane;
    const int ar0 = f0 >> 2, ar1 = f1 >> 2;                 // physical row 0..127
    const int kc0 = ((f0 & 3) ^ (ar0 & 3)) * 8;             // swizzled logical k-offset
    const int kc1 = ((f1 & 3) ^ (ar1 & 3)) * 8;
    size_t abase0, abase1;
    {
        int r0 = row0 + ar0, r1 = row0 + ar1;
        if (AMAP == 0) {
            abase0 = (size_t)min(r0, M - 1) * lda + kc0;
            abase1 = (size_t)min(r1, M - 1) * lda + kc1;
        } else if (AMAP == 1) {
            int m0 = min(r0, M - 1), m1 = min(r1, M - 1);
            int b0 = m0 / 497, l0 = m0 - b0 * 497;
            int b1 = m1 / 497, l1 = m1 - b1 * 497;
            abase0 = ((size_t)(b0 * 2000 + l0 * 4) << 8) + kc0;
            abase1 = ((size_t)(b1 * 2000 + l1 * 4) << 8) + kc1;
        } else {
            int b0 = r0 >> 11, t0 = min(r0 & 2047, 1999);
            int b1 = r1 >> 11, t1 = min(r1 & 2047, 1999);
            abase0 = ((size_t)(b0 * 2000 + t0) << 8) + kc0;
            abase1 = ((size_t)(b1 * 2000 + t1) << 8) + kc1;
        }
    }
    size_t bbase0 = (size_t)min(col0 + ar0, N - 1) * ldb + kc0;
    size_t bbase1 = (size_t)min(col0 + ar1, N - 1) * ldb + kc1;

    floatx4 acc[4][4];
    #pragma unroll
    for (int i = 0; i < 4; i++)
        #pragma unroll
        for (int j = 0; j < 4; j++) acc[i][j] = (floatx4){0.f, 0.f, 0.f, 0.f};

    const int mr = lane & 15;
    const int sw = ((lane >> 4) ^ (mr & 3)) * 8;            // swizzled read offset (shorts)

    for (int kt = k0; kt < kend; kt += 32) {
        __syncthreads();
        gload16(Ah + abase0 + kt, &AsH[slot0 * 512]);
        gload16(Ah + abase1 + kt, &AsH[slot1 * 512]);
        gload16(Al + abase0 + kt, &AsL[slot0 * 512]);
        gload16(Al + abase1 + kt, &AsL[slot1 * 512]);
        gload16(Bh + bbase0 + kt, &BsH[slot0 * 512]);
        gload16(Bh + bbase1 + kt, &BsH[slot1 * 512]);
        gload16(Bl + bbase0 + kt, &BsL[slot0 * 512]);
        gload16(Bl + bbase1 + kt, &BsL[slot1 * 512]);
        __syncthreads();
        short8 ah4[4], al4[4], bh4[4], bl4[4];
        #pragma unroll
        for (int i = 0; i < 4; i++) {
            int off = (wm * 64 + i * 16 + mr) * 32 + sw;
            ah4[i] = *(const short8*)&AsH[off];
            al4[i] = *(const short8*)&AsL[off];
        }
        #pragma unroll
        for (int j = 0; j < 4; j++) {
            int off = (wn * 64 + j * 16 + mr) * 32 + sw;
            bh4[j] = *(const short8*)&BsH[off];
            bl4[j] = *(const short8*)&BsL[off];
        }
        #pragma unroll
        for (int i = 0; i < 4; i++)
            #pragma unroll
            for (int j = 0; j < 4; j++)
                acc[i][j] = __builtin_amdgcn_mfma_f32_16x16x32_bf16(ah4[i], bh4[j], acc[i][j], 0, 0, 0);
        #pragma unroll
        for (int i = 0; i < 4; i++)
            #pragma unroll
            for (int j = 0; j < 4; j++)
                acc[i][j] = __builtin_amdgcn_mfma_f32_16x16x32_bf16(ah4[i], bl4[j], acc[i][j], 0, 0, 0);
        #pragma unroll
        for (int i = 0; i < 4; i++)
            #pragma unroll
            for (int j = 0; j < 4; j++)
                acc[i][j] = __builtin_amdgcn_mfma_f32_16x16x32_bf16(al4[i], bh4[j], acc[i][j], 0, 0, 0);
    }

    const int rq = (lane >> 4) * 4;
    #pragma unroll
    for (int i = 0; i < 4; i++) {
        #pragma unroll
        for (int j = 0; j < 4; j++) {
            int colg = col0 + wn * 64 + j * 16 + mr;
            if (colg >= N) continue;
            #pragma unroll
            for (int r = 0; r < 4; r++) {
                int rowg = row0 + wm * 64 + i * 16 + rq + r;
                if (SPLIT) {
                    if (rowg < M) Cf[(size_t)rowg * ldc + colg] = acc[i][j][r];
                    continue;
                }
                int orow; bool rok;
                if (AMAP == 2) {
                    int bb = rowg >> 11, t = rowg & 2047;
                    rok = (t < 2000);
                    orow = bb * 2000 + t;
                } else { rok = (rowg < M); orow = rowg; }
                if (!rok) continue;
                float v = acc[i][j][r];
                if (BIASF) v += bias[colg];
                if (ACT == 1) v = fmaxf(v, 0.f) + log1pf(expf(-fabsf(v)));
                if (ACT == 2) v = v / (1.f + fabsf(v));
                size_t oidx = (size_t)orow * ldc + colg;
                if (WF32) Cf[oidx] = v;
                if (WHL)  write_hilo(v, Ch + oidx, Cl + oidx);
            }
        }
    }
}

// ---------------------------------------------------------------------------
// Split-K reduction + bias/act + fp32/hilo writes
// ---------------------------------------------------------------------------
template<int WF32, int WHL, int BIASF, int ACT>
__global__ __launch_bounds__(256) void reduce_k(const float* __restrict__ Cp,
                                                size_t pstride, int nsplit,
                                                float* __restrict__ Cf,
                                                unsigned short* __restrict__ Ch,
                                                unsigned short* __restrict__ Cl,
                                                const float* __restrict__ bias,
                                                int N, int total)
{
    int i = blockIdx.x * 256 + threadIdx.x;
    if (i >= total) return;
    float v = 0.f;
    for (int z = 0; z < nsplit; z++) v += Cp[(size_t)z * pstride + i];
    if (BIASF) v += bias[i % N];
    if (ACT == 1) v = fmaxf(v, 0.f) + log1pf(expf(-fabsf(v)));
    if (WF32) Cf[i] = v;
    if (WHL)  write_hilo(v, Ch + i, Cl + i);
}

// ---------------------------------------------------------------------------
// Causal depthwise conv (k=4) + bias + SiLU
// ---------------------------------------------------------------------------
__global__ __launch_bounds__(256) void conv_silu_kernel(const float* __restrict__ XZ,
                                                        const float* __restrict__ cw,
                                                        const float* __restrict__ cb,
                                                        float* __restrict__ XC,
                                                        unsigned short* __restrict__ XCh,
                                                        unsigned short* __restrict__ XCl)
{
    int idx = blockIdx.x * 256 + threadIdx.x;   // 3976*1024
    if (idx >= MROWS * DINNER) return;
    int row = idx >> 10, c = idx & 1023;
    unsigned b = (unsigned)row / 497u;
    int l = row - (int)b * 497;
    float acc = cb[c];
    #pragma unroll
    for (int j = 0; j < 4; j++) {
        int lj = l - 3 + j;
        if (lj >= 0) acc += XZ[(size_t)(row - 3 + j) * 2048 + c] * cw[c * 4 + j];
    }
    float sig = 1.f / (1.f + expf(-acc));
    float v = acc * sig;
    XC[idx] = v;
    write_hilo(v, XCh + idx, XCl + idx);
}

// ---------------------------------------------------------------------------
// Chunked scan, phase 1: local scan from 0 + decay product
// ---------------------------------------------------------------------------
__global__ __launch_bounds__(256) void scan_part1(const float* __restrict__ DELTA,
                                                  const float* __restrict__ XC,
                                                  const float* __restrict__ XDBC,
                                                  const float* __restrict__ Alog,
                                                  float* __restrict__ SEnd,
                                                  float* __restrict__ Pp)
{
    __shared__ float sB[CSZ][16];
    int tid = threadIdx.x;
    int bid = blockIdx.x;
    int c = bid % NCH; int r = bid / NCH;
    int db = r & 3, b = r >> 2;
    int d = db * 256 + tid;
    int t0 = c * CSZ;
    int tcnt = min(CSZ, LOUT - t0);
    int rowbase = b * LOUT + t0;

    int li = tid >> 2, lj = (tid & 3) * 4;
    if (li < tcnt)
        *(float4*)&sB[li][lj] = *(const float4*)(XDBC + (size_t)(rowbase + li) * 64 + 32 + lj);
    __syncthreads();

    float a[DSTATE], cum[DSTATE], s[DSTATE];
    #pragma unroll
    for (int n = 0; n < DSTATE; n++) {
        a[n] = -expf(Alog[(size_t)d * DSTATE + n]);
        cum[n] = 1.f; s[n] = 0.f;
    }
    for (int tt = 0; tt < tcnt; tt++) {
        size_t row = (size_t)(rowbase + tt);
        float dv = DELTA[row * DINNER + d];
        float xv = XC[row * DINNER + d];
        float dx = dv * xv;
        #pragma unroll
        for (int n = 0; n < DSTATE; n++) {
            float e = expf(dv * a[n]);
            cum[n] *= e;
            s[n] = fmaf(e, s[n], dx * sB[tt][n]);
        }
    }
    size_t base = ((size_t)(c * 8 + b) * 16) * 1024 + d;
    #pragma unroll
    for (int n = 0; n < DSTATE; n++) {
        SEnd[base + (size_t)n * 1024] = s[n];
        Pp[base + (size_t)n * 1024]   = cum[n];
    }
}

// ---------------------------------------------------------------------------
// Chunked scan, phase 2: combine chunk summaries
// ---------------------------------------------------------------------------
__global__ __launch_bounds__(256) void scan_part2(const float* __restrict__ SEnd,
                                                  const float* __restrict__ Pp,
                                                  float* __restrict__ SIn)
{
    int tid = threadIdx.x;
    int bid = blockIdx.x;           // 512 = 8b * 16n * 4db
    int db = bid & 3, n = (bid >> 2) & 15, b = bid >> 6;
    int d = db * 256 + tid;
    float s = 0.f;
    for (int c = 0; c < NCH; c++) {
        size_t idx = ((size_t)(c * 8 + b) * 16 + n) * 1024 + d;
        SIn[idx] = s;
        s = fmaf(Pp[idx], s, SEnd[idx]);
    }
}

// ---------------------------------------------------------------------------
// Chunked scan, phase 3: recompute with incoming state, emit gated y (hilo)
// ---------------------------------------------------------------------------
__global__ __launch_bounds__(256) void scan_part3(const float* __restrict__ DELTA,
                                                  const float* __restrict__ XC,
                                                  const float* __restrict__ XZ,
                                                  const float* __restrict__ XDBC,
                                                  const float* __restrict__ Alog,
                                                  const float* __restrict__ Dp,
                                                  const float* __restrict__ SIn,
                                                  unsigned short* __restrict__ Yh,
                                                  unsigned short* __restrict__ Yl)
{
    __shared__ float sBC[CSZ][32];
    int tid = threadIdx.x;
    int bid = blockIdx.x;
    int c = bid % NCH; int r = bid / NCH;
    int db = r & 3, b = r >> 2;
    int d = db * 256 + tid;
    int t0 = c * CSZ;
    int tcnt = min(CSZ, LOUT - t0);
    int rowbase = b * LOUT + t0;

    int li = tid >> 3, lj = (tid & 7) * 4;
    if (li < tcnt)
        *(float4*)&sBC[li][lj] = *(const float4*)(XDBC + (size_t)(rowbase + li) * 64 + 32 + lj);
    int li2 = li + 32;
    if (li2 < tcnt)
        *(float4*)&sBC[li2][lj] = *(const float4*)(XDBC + (size_t)(rowbase + li2) * 64 + 32 + lj);
    __syncthreads();

    float a[DSTATE], s[DSTATE];
    size_t base = ((size_t)(c * 8 + b) * 16) * 1024 + d;
    #pragma unroll
    for (int n = 0; n < DSTATE; n++) {
        a[n] = -expf(Alog[(size_t)d * DSTATE + n]);
        s[n] = SIn[base + (size_t)n * 1024];
    }
    float dD = Dp[d];

    for (int tt = 0; tt < tcnt; tt++) {
        size_t row = (size_t)(rowbase + tt);
        float dv = DELTA[row * DINNER + d];
        float xv = XC[row * DINNER + d];
        float zv = XZ[row * 2048 + DINNER + d];
        float dx = dv * xv;
        float y = 0.f;
        #pragma unroll
        for (int n = 0; n < DSTATE; n++) {
            float e = expf(dv * a[n]);
            s[n] = fmaf(e, s[n], dx * sBC[tt][n]);
            y = fmaf(s[n], sBC[tt][DSTATE + n], y);
        }
        float g = zv / (1.f + expf(-zv));
        float yv = (y + xv * dD) * g;
        write_hilo(yv, Yh + row * DINNER + d, Yl + row * DINNER + d);
    }
}

// ---------------------------------------------------------------------------
extern "C" void kernel_launch(void* const* d_in, const int* in_sizes, int n_in,
                              void* d_out, int out_size, void* d_ws, size_t ws_size,
                              hipStream_t stream)
{
    const float* neuralInput = (const float*)d_in[0];
    const int*   dayIdx      = (const int*)  d_in[1];
    const float* day_w       = (const float*)d_in[2];
    const float* day_b       = (const float*)d_in[3];
    const float* lin_in_w    = (const float*)d_in[4];
    const float* lin_in_b    = (const float*)d_in[5];
    const float* in_proj_w   = (const float*)d_in[6];
    const float* conv_w      = (const float*)d_in[7];
    const float* conv_b      = (const float*)d_in[8];
    const float* x_proj_w    = (const float*)d_in[9];
    const float* dt_w        = (const float*)d_in[10];
    const float* dt_b        = (const float*)d_in[11];
    const float* A_log       = (const float*)d_in[12];
    const float* D_param     = (const float*)d_in[13];
    const float* out_proj_w  = (const float*)d_in[14];
    const float* fc_w        = (const float*)d_in[15];
    const float* fc_b        = (const float*)d_in[16];
    float* out = (float*)d_out;

    // ---------------- workspace layout (floats) ----------------
    float* p = (float*)d_ws;
    float* xz    = p; p += (size_t)MROWS * 2048;          // 8,142,848
    float* xconv = p; p += (size_t)MROWS * DINNER;        // 4,071,424
    float* delta = p; p += (size_t)MROWS * DINNER;        // 4,071,424
    float* xdbc  = p; p += (size_t)MROWS * 64;            //   254,464
    unsigned short* Hh = (unsigned short*)p;              // h hi/lo (3976x512)
    unsigned short* Hl = Hh + (size_t)MROWS * DMODEL;
    p += (size_t)MROWS * DMODEL;
    unsigned short* XSh = (unsigned short*)p;             // smooth out hi/lo
    unsigned short* XSl = XSh + (size_t)BATCH * TLEN * NDIM;
    p += (size_t)BATCH * TLEN * NDIM;
    unsigned short* XCh = XSh;                            // alias: conv out hi/lo
    unsigned short* XCl = XCh + (size_t)MROWS * DINNER;
    float* xdreg = p;                                     // day-out region
    unsigned short* XDh = (unsigned short*)p;
    unsigned short* XDl = XDh + (size_t)BATCH * TLEN * NDIM;
    p += (size_t)BATCH * TLEN * NDIM;
    unsigned short* Yh = XDh;                             // alias: scan out hi/lo
    unsigned short* Yl = Yh + (size_t)MROWS * DINNER;
    float* SEnd = xdreg;                                  // alias (dead before phase C)
    float* Pp   = SEnd + (size_t)NCH * 8 * 16 * 1024;
    unsigned short* Dh = (unsigned short*)p;              // xdbc hi/lo (3976x64)
    unsigned short* Dl = Dh + (size_t)MROWS * 64;
    p += (size_t)MROWS * 64;
    unsigned short* Wh = (unsigned short*)p;              // weight scratch hi/lo
    unsigned short* Wl = Wh + 1835008;
    float* SIn = (float*)Wh;                              // alias
    p += 1835008;
    float* daybias = p; p += 2048;
    // split-K partial aliases (regions dead at the time of use)
    float* bigpart = xz;      // lin_in (pre-loop) and out_proj (post-scan): 4 x 3976 x 512
    float* smlpart = delta;   // x_proj (pre-dt): 8 x 3976 x 64 ; fc (post-loop): 4 x 3976 x 41

    // 1. smooth -> XShl
    smooth_kernel<<<dim3((BATCH*TLEN*NDIM)/256), 256, 0, stream>>>(neuralInput, XSh, XSl);
    // 2. day weights repack + day GEMM (softsign) -> XDhl
    repack_day<<<dim3((8*65536)/256), 256, 0, stream>>>(day_w, day_b, dayIdx, Wh, Wl, daybias);
    mfma_gemm3<0,1,1,2,2,0><<<dim3(128, 2), 256, 0, stream>>>(
        XSh, XSl, 256, Wh, Wl, 256, nullptr, XDh, XDl, 256, daybias, 16000, 256, 256, 0);
    // 3. lin_in repack + split-K GEMM -> Hhl
    repack_linin<<<dim3((512*3584)/256), 256, 0, stream>>>(lin_in_w, Wh, Wl);
    mfma_gemm3<0,0,0,0,1,1><<<dim3(32, 4, 4), 256, 0, stream>>>(
        XDh, XDl, 0, Wh, Wl, 3584, bigpart, nullptr, nullptr, DMODEL, nullptr,
        MROWS, DMODEL, 3584, 896);
    reduce_k<0,1,1,0><<<dim3((MROWS*DMODEL)/256), 256, 0, stream>>>(
        bigpart, (size_t)MROWS*DMODEL, 4, nullptr, Hh, Hl, lin_in_b, DMODEL, MROWS*DMODEL);

    for (int l = 0; l < LAYERS; l++) {
        const float* ipw = in_proj_w  + (size_t)l * 2048 * DMODEL;
        const float* cwl = conv_w     + (size_t)l * DINNER * 4;
        const float* cbl = conv_b     + (size_t)l * DINNER;
        const float* xpw = x_proj_w   + (size_t)l * 64 * DINNER;
        const float* dtw = dt_w       + (size_t)l * DINNER * DTRANK;
        const float* dtb = dt_b       + (size_t)l * DINNER;
        const float* alg = A_log      + (size_t)l * DINNER * DSTATE;
        const float* dpl = D_param    + (size_t)l * DINNER;
        const float* opw = out_proj_w + (size_t)l * DMODEL * DINNER;

        // in_proj: (3976x512)@(2048x512)^T -> xz fp32
        convw_kernel<<<dim3((2048*512)/256), 256, 0, stream>>>(ipw, Wh, Wl, 2048*512);
        mfma_gemm3<1,0,0,0,0,0><<<dim3(32, 16), 256, 0, stream>>>(
            Hh, Hl, DMODEL, Wh, Wl, DMODEL, xz, nullptr, nullptr, 2048, nullptr,
            MROWS, 2048, DMODEL, 0);
        // conv + silu -> xconv fp32 + XChl
        conv_silu_kernel<<<dim3((MROWS*DINNER)/256), 256, 0, stream>>>(xz, cwl, cbl,
                                                                       xconv, XCh, XCl);
        // x_proj: split-K 8 -> xdbc fp32 + Dhl
        convw_kernel<<<dim3((64*1024)/256), 256, 0, stream>>>(xpw, Wh, Wl, 64*1024);
        mfma_gemm3<0,0,0,0,0,1><<<dim3(32, 1, 8), 256, 0, stream>>>(
            XCh, XCl, DINNER, Wh, Wl, DINNER, smlpart, nullptr, nullptr, 64, nullptr,
            MROWS, 64, DINNER, 128);
        reduce_k<1,1,0,0><<<dim3((MROWS*64)/256), 256, 0, stream>>>(
            smlpart, (size_t)MROWS*64, 8, xdbc, Dh, Dl, nullptr, 64, MROWS*64);
        // dt: (3976x32, lda=64)@(1024x32)^T + bias, softplus -> delta fp32
        convw_kernel<<<dim3((1024*32)/256), 256, 0, stream>>>(dtw, Wh, Wl, 1024*32);
        mfma_gemm3<1,0,1,1,0,0><<<dim3(32, 8), 256, 0, stream>>>(
            Dh, Dl, 64, Wh, Wl, DTRANK, delta, nullptr, nullptr, DINNER, dtb,
            MROWS, DINNER, DTRANK, 0);
        // chunked scan -> Yhl
        scan_part1<<<dim3(8*4*NCH), 256, 0, stream>>>(delta, xconv, xdbc, alg, SEnd, Pp);
        scan_part2<<<dim3(512), 256, 0, stream>>>(SEnd, Pp, SIn);
        scan_part3<<<dim3(8*4*NCH), 256, 0, stream>>>(delta, xconv, xz, xdbc, alg, dpl,
                                                      SIn, Yh, Yl);
        // out_proj: split-K 4 -> Hhl
        convw_kernel<<<dim3((512*1024)/256), 256, 0, stream>>>(opw, Wh, Wl, 512*1024);
        mfma_gemm3<0,0,0,0,0,1><<<dim3(32, 4, 4), 256, 0, stream>>>(
            Yh, Yl, DINNER, Wh, Wl, DINNER, bigpart, nullptr, nullptr, DMODEL, nullptr,
            MROWS, DMODEL, DINNER, 256);
        reduce_k<0,1,0,0><<<dim3((MROWS*DMODEL)/256), 256, 0, stream>>>(
            bigpart, (size_t)MROWS*DMODEL, 4, nullptr, Hh, Hl, nullptr, DMODEL, MROWS*DMODEL);
    }

    // fc: split-K 4 -> out (3976 x 41) fp32 + bias
    convw_kernel<<<dim3((NCLS*DMODEL+255)/256), 256, 0, stream>>>(fc_w, Wh, Wl, NCLS*DMODEL);
    mfma_gemm3<0,0,0,0,0,1><<<dim3(32, 1, 4), 256, 0, stream>>>(
        Hh, Hl, DMODEL, Wh, Wl, DMODEL, smlpart, nullptr, nullptr, NCLS, nullptr,
        MROWS, NCLS, DMODEL, 128);
    reduce_k<1,0,1,0><<<dim3((MROWS*NCLS+255)/256), 256, 0, stream>>>(
        smlpart, (size_t)MROWS*NCLS, 4, out, nullptr, nullptr, fc_b, NCLS, MROWS*NCLS);
}

// Round 5
// 1234.875 us; speedup vs baseline: 3.3017x; 1.0173x over previous
//
#include <hip/hip_runtime.h>
#include <math.h>

#define NDIM    256
#define DMODEL  512
#define DSTATE  16
#define KLEN    14
#define DINNER  1024
#define DTRANK  32
#define BATCH   8
#define TLEN    2000
#define LOUT    497
#define MROWS   (BATCH*LOUT)   // 3976
#define NCLS    41
#define LAYERS  4
#define NCH     25
#define CSZ     20

typedef __attribute__((ext_vector_type(8))) short short8;
typedef __attribute__((ext_vector_type(4))) float floatx4;

// ---------------- bf16 split helpers (RNE) ----------------
__device__ inline unsigned short bf16_rne(float f) {
    unsigned int u = __float_as_uint(f);
    u += 0x7fffu + ((u >> 16) & 1u);
    return (unsigned short)(u >> 16);
}
__device__ inline float bf16_to_f(unsigned short h) {
    return __uint_as_float(((unsigned int)h) << 16);
}
__device__ inline void write_hilo(float v, unsigned short* ph, unsigned short* pl) {
    unsigned short h = bf16_rne(v);
    *ph = h;
    *pl = bf16_rne(v - bf16_to_f(h));
}

__device__ inline void gload16(const unsigned short* g, unsigned short* l) {
    __builtin_amdgcn_global_load_lds((const __attribute__((address_space(1))) void*)g,
                                     (__attribute__((address_space(3))) void*)l,
                                     16, 0, 0);
}

// ---------------------------------------------------------------------------
// Gaussian smoothing -> bf16 hi/lo
// ---------------------------------------------------------------------------
__global__ __launch_bounds__(256) void smooth_kernel(const float* __restrict__ X,
                                                     unsigned short* __restrict__ XSh,
                                                     unsigned short* __restrict__ XSl)
{
    __shared__ float w[20];
    int tid = threadIdx.x;
    if (tid < 20) {
        float t = ((float)tid - 9.5f) * 0.5f;
        w[tid] = expf(-0.5f * t * t);
    }
    __syncthreads();
    float s = 0.f;
    #pragma unroll
    for (int j = 0; j < 20; j++) s += w[j];
    float inv = 1.f / s;

    int idx = blockIdx.x * 256 + tid;
    if (idx >= BATCH * TLEN * NDIM) return;
    int d  = idx & 255;
    int bt = idx >> 8;
    int b  = bt / TLEN;
    int tt = bt - b * TLEN;
    const float* Xb = X + ((size_t)b * TLEN) * NDIM + d;
    float acc = 0.f;
    #pragma unroll
    for (int j = 0; j < 20; j++) {
        int t2 = tt - 9 + j;
        if (t2 >= 0 && t2 < TLEN) acc += Xb[(size_t)t2 * NDIM] * w[j];
    }
    write_hilo(acc * inv, XSh + idx, XSl + idx);
}

// ---------------------------------------------------------------------------
// Repack day weights for the 8 selected days (transposed, hi/lo) + bias
// ---------------------------------------------------------------------------
__global__ __launch_bounds__(256) void repack_day(const float* __restrict__ day_w,
                                                  const float* __restrict__ day_b,
                                                  const int*   __restrict__ dayIdx,
                                                  unsigned short* __restrict__ Wh,
                                                  unsigned short* __restrict__ Wl,
                                                  float* __restrict__ biasbuf)
{
    int idx = blockIdx.x * 256 + threadIdx.x;   // 8*65536
    if (idx >= 8 * 65536) return;
    int b = idx >> 16;
    int rem = idx & 65535;
    int n = rem >> 8, k = rem & 255;
    int day = dayIdx[b];
    float v = day_w[(size_t)day * 65536 + (size_t)k * 256 + n];
    write_hilo(v, Wh + idx, Wl + idx);
    if (rem < 256) biasbuf[b * 256 + rem] = day_b[(size_t)day * 256 + rem];
}

// ---------------------------------------------------------------------------
// Repack lin_in_w with K reordered as kk' = r*256 + dd
// ---------------------------------------------------------------------------
__global__ __launch_bounds__(256) void repack_linin(const float* __restrict__ W,
                                                    unsigned short* __restrict__ Wh,
                                                    unsigned short* __restrict__ Wl)
{
    int idx = blockIdx.x * 256 + threadIdx.x;   // 512*3584
    if (idx >= 512 * 3584) return;
    int o = idx / 3584;
    int kk = idx - o * 3584;
    int r = kk >> 8, dd = kk & 255;
    float v = W[(size_t)o * 3584 + dd * 14 + r];
    write_hilo(v, Wh + idx, Wl + idx);
}

// ---------------------------------------------------------------------------
// Generic fp32 -> bf16 hi/lo conversion (weights)
// ---------------------------------------------------------------------------
__global__ __launch_bounds__(256) void convw_kernel(const float* __restrict__ src,
                                                    unsigned short* __restrict__ dh,
                                                    unsigned short* __restrict__ dl,
                                                    int n)
{
    int i = blockIdx.x * 256 + threadIdx.x;
    if (i < n) write_hilo(src[i], dh + i, dl + i);
}

// ---------------------------------------------------------------------------
// Fused bf16x3 MFMA GEMM: single K-pass, 4 LDS tiles, 48 MFMA per BK=32 step.
// ---------------------------------------------------------------------------
template<int WF32, int WHL, int BIASF, int ACT, int AMAP, int SPLIT>
__global__ __launch_bounds__(256) void mfma_gemm3(
    const unsigned short* __restrict__ Ah, const unsigned short* __restrict__ Al, int lda,
    const unsigned short* __restrict__ Bh, const unsigned short* __restrict__ Bl, int ldb,
    float* __restrict__ Cf, unsigned short* __restrict__ Ch, unsigned short* __restrict__ Cl,
    int ldc, const float* __restrict__ bias, int M, int N, int K, int Kc)
{
    __shared__ __align__(16) unsigned short AsH[4096];
    __shared__ __align__(16) unsigned short AsL[4096];
    __shared__ __align__(16) unsigned short BsH[4096];
    __shared__ __align__(16) unsigned short BsL[4096];
    const int tid  = threadIdx.x;
    const int wave = tid >> 6, lane = tid & 63;
    const int wm = wave & 1, wn = wave >> 1;
    const int row0 = blockIdx.x * 128, col0 = blockIdx.y * 128;

    if (AMAP == 2) {
        int bb = row0 >> 11;
        Bh += (size_t)bb * 65536; Bl += (size_t)bb * 65536; bias += bb * 256;
    }

    int k0 = 0, kend = K;
    if (SPLIT) {
        k0 = blockIdx.z * Kc;
        kend = min(K, k0 + Kc);
        Cf += (size_t)blockIdx.z * (size_t)M * ldc;
    }

    const int slot0 = wave * 2, slot1 = wave * 2 + 1;
    const int f0 = slot0 * 64 + lane, f1 = slot1 * 64 + lane;
    const int ar0 = f0 >> 2, ar1 = f1 >> 2;
    const int kc0 = ((f0 & 3) ^ (ar0 & 3)) * 8;
    const int kc1 = ((f1 & 3) ^ (ar1 & 3)) * 8;
    size_t abase0, abase1;
    {
        int r0 = row0 + ar0, r1 = row0 + ar1;
        if (AMAP == 0) {
            abase0 = (size_t)min(r0, M - 1) * lda + kc0;
            abase1 = (size_t)min(r1, M - 1) * lda + kc1;
        } else if (AMAP == 1) {
            int m0 = min(r0, M - 1), m1 = min(r1, M - 1);
            int b0 = m0 / 497, l0 = m0 - b0 * 497;
            int b1 = m1 / 497, l1 = m1 - b1 * 497;
            abase0 = ((size_t)(b0 * 2000 + l0 * 4) << 8) + kc0;
            abase1 = ((size_t)(b1 * 2000 + l1 * 4) << 8) + kc1;
        } else {
            int b0 = r0 >> 11, t0 = min(r0 & 2047, 1999);
            int b1 = r1 >> 11, t1 = min(r1 & 2047, 1999);
            abase0 = ((size_t)(b0 * 2000 + t0) << 8) + kc0;
            abase1 = ((size_t)(b1 * 2000 + t1) << 8) + kc1;
        }
    }
    size_t bbase0 = (size_t)min(col0 + ar0, N - 1) * ldb + kc0;
    size_t bbase1 = (size_t)min(col0 + ar1, N - 1) * ldb + kc1;

    floatx4 acc[4][4];
    #pragma unroll
    for (int i = 0; i < 4; i++)
        #pragma unroll
        for (int j = 0; j < 4; j++) acc[i][j] = (floatx4){0.f, 0.f, 0.f, 0.f};

    const int mr = lane & 15;
    const int sw = ((lane >> 4) ^ (mr & 3)) * 8;

    for (int kt = k0; kt < kend; kt += 32) {
        __syncthreads();
        gload16(Ah + abase0 + kt, &AsH[slot0 * 512]);
        gload16(Ah + abase1 + kt, &AsH[slot1 * 512]);
        gload16(Al + abase0 + kt, &AsL[slot0 * 512]);
        gload16(Al + abase1 + kt, &AsL[slot1 * 512]);
        gload16(Bh + bbase0 + kt, &BsH[slot0 * 512]);
        gload16(Bh + bbase1 + kt, &BsH[slot1 * 512]);
        gload16(Bl + bbase0 + kt, &BsL[slot0 * 512]);
        gload16(Bl + bbase1 + kt, &BsL[slot1 * 512]);
        __syncthreads();
        short8 ah4[4], al4[4], bh4[4], bl4[4];
        #pragma unroll
        for (int i = 0; i < 4; i++) {
            int off = (wm * 64 + i * 16 + mr) * 32 + sw;
            ah4[i] = *(const short8*)&AsH[off];
            al4[i] = *(const short8*)&AsL[off];
        }
        #pragma unroll
        for (int j = 0; j < 4; j++) {
            int off = (wn * 64 + j * 16 + mr) * 32 + sw;
            bh4[j] = *(const short8*)&BsH[off];
            bl4[j] = *(const short8*)&BsL[off];
        }
        #pragma unroll
        for (int i = 0; i < 4; i++)
            #pragma unroll
            for (int j = 0; j < 4; j++)
                acc[i][j] = __builtin_amdgcn_mfma_f32_16x16x32_bf16(ah4[i], bh4[j], acc[i][j], 0, 0, 0);
        #pragma unroll
        for (int i = 0; i < 4; i++)
            #pragma unroll
            for (int j = 0; j < 4; j++)
                acc[i][j] = __builtin_amdgcn_mfma_f32_16x16x32_bf16(ah4[i], bl4[j], acc[i][j], 0, 0, 0);
        #pragma unroll
        for (int i = 0; i < 4; i++)
            #pragma unroll
            for (int j = 0; j < 4; j++)
                acc[i][j] = __builtin_amdgcn_mfma_f32_16x16x32_bf16(al4[i], bh4[j], acc[i][j], 0, 0, 0);
    }

    const int rq = (lane >> 4) * 4;
    #pragma unroll
    for (int i = 0; i < 4; i++) {
        #pragma unroll
        for (int j = 0; j < 4; j++) {
            int colg = col0 + wn * 64 + j * 16 + mr;
            if (colg >= N) continue;
            #pragma unroll
            for (int r = 0; r < 4; r++) {
                int rowg = row0 + wm * 64 + i * 16 + rq + r;
                if (SPLIT) {
                    if (rowg < M) Cf[(size_t)rowg * ldc + colg] = acc[i][j][r];
                    continue;
                }
                int orow; bool rok;
                if (AMAP == 2) {
                    int bb = rowg >> 11, t = rowg & 2047;
                    rok = (t < 2000);
                    orow = bb * 2000 + t;
                } else { rok = (rowg < M); orow = rowg; }
                if (!rok) continue;
                float v = acc[i][j][r];
                if (BIASF) v += bias[colg];
                if (ACT == 1) v = fmaxf(v, 0.f) + log1pf(expf(-fabsf(v)));
                if (ACT == 2) v = v / (1.f + fabsf(v));
                size_t oidx = (size_t)orow * ldc + colg;
                if (WF32) Cf[oidx] = v;
                if (WHL)  write_hilo(v, Ch + oidx, Cl + oidx);
            }
        }
    }
}

// ---------------------------------------------------------------------------
// Split-K reduction + bias/act + fp32/hilo writes
// ---------------------------------------------------------------------------
template<int WF32, int WHL, int BIASF, int ACT>
__global__ __launch_bounds__(256) void reduce_k(const float* __restrict__ Cp,
                                                size_t pstride, int nsplit,
                                                float* __restrict__ Cf,
                                                unsigned short* __restrict__ Ch,
                                                unsigned short* __restrict__ Cl,
                                                const float* __restrict__ bias,
                                                int N, int total)
{
    int i = blockIdx.x * 256 + threadIdx.x;
    if (i >= total) return;
    float v = 0.f;
    for (int z = 0; z < nsplit; z++) v += Cp[(size_t)z * pstride + i];
    if (BIASF) v += bias[i % N];
    if (ACT == 1) v = fmaxf(v, 0.f) + log1pf(expf(-fabsf(v)));
    if (WF32) Cf[i] = v;
    if (WHL)  write_hilo(v, Ch + i, Cl + i);
}

// ---------------------------------------------------------------------------
// Causal depthwise conv (k=4) + bias + SiLU -> hi/lo only (x_proj A operand)
// ---------------------------------------------------------------------------
__global__ __launch_bounds__(256) void conv_silu_kernel(const float* __restrict__ XZ,
                                                        const float* __restrict__ cw,
                                                        const float* __restrict__ cb,
                                                        unsigned short* __restrict__ XCh,
                                                        unsigned short* __restrict__ XCl)
{
    int idx = blockIdx.x * 256 + threadIdx.x;   // 3976*1024
    if (idx >= MROWS * DINNER) return;
    int row = idx >> 10, c = idx & 1023;
    unsigned b = (unsigned)row / 497u;
    int l = row - (int)b * 497;
    float acc = cb[c];
    #pragma unroll
    for (int j = 0; j < 4; j++) {
        int lj = l - 3 + j;
        if (lj >= 0) acc += XZ[(size_t)(row - 3 + j) * 2048 + c] * cw[c * 4 + j];
    }
    float sig = 1.f / (1.f + expf(-acc));
    float v = acc * sig;
    write_hilo(v, XCh + idx, XCl + idx);
}

// ---------------------------------------------------------------------------
// Scan phase 1: fused dt-dot + softplus + conv/SiLU + local scan from 0.
// ---------------------------------------------------------------------------
__global__ __launch_bounds__(256) void scan_part1(const float* __restrict__ XZ,
                                                  const float* __restrict__ XDBC,
                                                  const float* __restrict__ dtw,
                                                  const float* __restrict__ dtb,
                                                  const float* __restrict__ cw,
                                                  const float* __restrict__ cb,
                                                  const float* __restrict__ Alog,
                                                  float* __restrict__ SEnd,
                                                  float* __restrict__ Pp)
{
    __shared__ float sR[CSZ][64];
    int tid = threadIdx.x;
    int bid = blockIdx.x;
    int c = bid % NCH; int r = bid / NCH;
    int db = r & 3, b = r >> 2;
    int d = db * 256 + tid;
    int t0 = c * CSZ;
    int tcnt = min(CSZ, LOUT - t0);
    int rowbase = b * LOUT + t0;

    int li = tid >> 4, lj = (tid & 15) * 4;
    if (li < tcnt)
        *(float4*)&sR[li][lj] = *(const float4*)(XDBC + (size_t)(rowbase + li) * 64 + lj);
    if (li + 16 < tcnt)
        *(float4*)&sR[li + 16][lj] = *(const float4*)(XDBC + (size_t)(rowbase + li + 16) * 64 + lj);
    __syncthreads();

    float w[32];
    #pragma unroll
    for (int k = 0; k < 8; k++)
        *(float4*)&w[k * 4] = *(const float4*)(dtw + (size_t)d * 32 + k * 4);
    float dtbv = dtb[d];
    float4 cwv = *(const float4*)(cw + (size_t)d * 4);
    float cbv = cb[d];

    float a[DSTATE], cum[DSTATE], s[DSTATE];
    #pragma unroll
    for (int n = 0; n < DSTATE; n++) {
        a[n] = -expf(Alog[(size_t)d * DSTATE + n]);
        cum[n] = 1.f; s[n] = 0.f;
    }

    const float* Xp = XZ + d;   // x half, stride 2048
    float xm1 = 0.f, xm2 = 0.f, xm3 = 0.f;
    if (t0 >= 1) xm1 = Xp[(size_t)(rowbase - 1) * 2048];
    if (t0 >= 2) xm2 = Xp[(size_t)(rowbase - 2) * 2048];
    if (t0 >= 3) xm3 = Xp[(size_t)(rowbase - 3) * 2048];
    float xr = Xp[(size_t)rowbase * 2048];

    for (int tt = 0; tt < tcnt; tt++) {
        float xr_n = (tt + 1 < tcnt) ? Xp[(size_t)(rowbase + tt + 1) * 2048] : 0.f;
        float dot = dtbv;
        #pragma unroll
        for (int k = 0; k < 32; k++) dot = fmaf(sR[tt][k], w[k], dot);
        float dv = fmaxf(dot, 0.f) + log1pf(expf(-fabsf(dot)));
        float pre = cbv + cwv.x * xm3 + cwv.y * xm2 + cwv.z * xm1 + cwv.w * xr;
        float xv = pre / (1.f + expf(-pre));
        float dx = dv * xv;
        #pragma unroll
        for (int n = 0; n < DSTATE; n++) {
            float e = expf(dv * a[n]);
            cum[n] *= e;
            s[n] = fmaf(e, s[n], dx * sR[tt][32 + n]);
        }
        xm3 = xm2; xm2 = xm1; xm1 = xr; xr = xr_n;
    }
    size_t base = ((size_t)(c * 8 + b) * 16) * 1024 + d;
    #pragma unroll
    for (int n = 0; n < DSTATE; n++) {
        SEnd[base + (size_t)n * 1024] = s[n];
        Pp[base + (size_t)n * 1024]   = cum[n];
    }
}

// ---------------------------------------------------------------------------
// Scan phase 2: combine chunk summaries; SIn written in place over Pp.
// ---------------------------------------------------------------------------
__global__ __launch_bounds__(256) void scan_part2(const float* __restrict__ SEnd,
                                                  float* __restrict__ PS)
{
    int tid = threadIdx.x;
    int bid = blockIdx.x;           // 512 = 8b * 16n * 4db
    int db = bid & 3, n = (bid >> 2) & 15, b = bid >> 6;
    int d = db * 256 + tid;
    float s = 0.f;
    for (int c = 0; c < NCH; c++) {
        size_t idx = ((size_t)(c * 8 + b) * 16 + n) * 1024 + d;
        float pc = PS[idx];
        float se = SEnd[idx];
        PS[idx] = s;
        s = fmaf(pc, s, se);
    }
}

// ---------------------------------------------------------------------------
// Scan phase 3: fused dt/conv recompute with true incoming state, emit gated y
// ---------------------------------------------------------------------------
__global__ __launch_bounds__(256) void scan_part3(const float* __restrict__ XZ,
                                                  const float* __restrict__ XDBC,
                                                  const float* __restrict__ dtw,
                                                  const float* __restrict__ dtb,
                                                  const float* __restrict__ cw,
                                                  const float* __restrict__ cb,
                                                  const float* __restrict__ Alog,
                                                  const float* __restrict__ Dp,
                                                  const float* __restrict__ SIn,
                                                  unsigned short* __restrict__ Yh,
                                                  unsigned short* __restrict__ Yl)
{
    __shared__ float sR[CSZ][64];
    int tid = threadIdx.x;
    int bid = blockIdx.x;
    int c = bid % NCH; int r = bid / NCH;
    int db = r & 3, b = r >> 2;
    int d = db * 256 + tid;
    int t0 = c * CSZ;
    int tcnt = min(CSZ, LOUT - t0);
    int rowbase = b * LOUT + t0;

    int li = tid >> 4, lj = (tid & 15) * 4;
    if (li < tcnt)
        *(float4*)&sR[li][lj] = *(const float4*)(XDBC + (size_t)(rowbase + li) * 64 + lj);
    if (li + 16 < tcnt)
        *(float4*)&sR[li + 16][lj] = *(const float4*)(XDBC + (size_t)(rowbase + li + 16) * 64 + lj);
    __syncthreads();

    float w[32];
    #pragma unroll
    for (int k = 0; k < 8; k++)
        *(float4*)&w[k * 4] = *(const float4*)(dtw + (size_t)d * 32 + k * 4);
    float dtbv = dtb[d];
    float4 cwv = *(const float4*)(cw + (size_t)d * 4);
    float cbv = cb[d];
    float dD = Dp[d];

    float a[DSTATE], s[DSTATE];
    size_t base = ((size_t)(c * 8 + b) * 16) * 1024 + d;
    #pragma unroll
    for (int n = 0; n < DSTATE; n++) {
        a[n] = -expf(Alog[(size_t)d * DSTATE + n]);
        s[n] = SIn[base + (size_t)n * 1024];
    }

    const float* Xp = XZ + d;          // x half
    const float* Zp = XZ + 1024 + d;   // z half
    float xm1 = 0.f, xm2 = 0.f, xm3 = 0.f;
    if (t0 >= 1) xm1 = Xp[(size_t)(rowbase - 1) * 2048];
    if (t0 >= 2) xm2 = Xp[(size_t)(rowbase - 2) * 2048];
    if (t0 >= 3) xm3 = Xp[(size_t)(rowbase - 3) * 2048];
    float xr = Xp[(size_t)rowbase * 2048];
    float zr = Zp[(size_t)rowbase * 2048];

    for (int tt = 0; tt < tcnt; tt++) {
        float xr_n = 0.f, zr_n = 0.f;
        if (tt + 1 < tcnt) {
            xr_n = Xp[(size_t)(rowbase + tt + 1) * 2048];
            zr_n = Zp[(size_t)(rowbase + tt + 1) * 2048];
        }
        float dot = dtbv;
        #pragma unroll
        for (int k = 0; k < 32; k++) dot = fmaf(sR[tt][k], w[k], dot);
        float dv = fmaxf(dot, 0.f) + log1pf(expf(-fabsf(dot)));
        float pre = cbv + cwv.x * xm3 + cwv.y * xm2 + cwv.z * xm1 + cwv.w * xr;
        float xv = pre / (1.f + expf(-pre));
        float dx = dv * xv;
        float y = 0.f;
        #pragma unroll
        for (int n = 0; n < DSTATE; n++) {
            float e = expf(dv * a[n]);
            s[n] = fmaf(e, s[n], dx * sR[tt][32 + n]);
            y = fmaf(s[n], sR[tt][48 + n], y);
        }
        float g = zr / (1.f + expf(-zr));
        float yv = (y + xv * dD) * g;
        size_t row = (size_t)(rowbase + tt);
        write_hilo(yv, Yh + row * DINNER + d, Yl + row * DINNER + d);
        xm3 = xm2; xm2 = xm1; xm1 = xr; xr = xr_n; zr = zr_n;
    }
}

// ---------------------------------------------------------------------------
extern "C" void kernel_launch(void* const* d_in, const int* in_sizes, int n_in,
                              void* d_out, int out_size, void* d_ws, size_t ws_size,
                              hipStream_t stream)
{
    const float* neuralInput = (const float*)d_in[0];
    const int*   dayIdx      = (const int*)  d_in[1];
    const float* day_w       = (const float*)d_in[2];
    const float* day_b       = (const float*)d_in[3];
    const float* lin_in_w    = (const float*)d_in[4];
    const float* lin_in_b    = (const float*)d_in[5];
    const float* in_proj_w   = (const float*)d_in[6];
    const float* conv_w      = (const float*)d_in[7];
    const float* conv_b      = (const float*)d_in[8];
    const float* x_proj_w    = (const float*)d_in[9];
    const float* dt_w        = (const float*)d_in[10];
    const float* dt_b        = (const float*)d_in[11];
    const float* A_log       = (const float*)d_in[12];
    const float* D_param     = (const float*)d_in[13];
    const float* out_proj_w  = (const float*)d_in[14];
    const float* fc_w        = (const float*)d_in[15];
    const float* fc_b        = (const float*)d_in[16];
    float* out = (float*)d_out;

    // ---------------- workspace layout (floats) ----------------
    float* p = (float*)d_ws;
    float* xz   = p; p += (size_t)MROWS * 2048;           // 8,142,848
    float* xcv  = p; p += (size_t)MROWS * DINNER;         // 4,071,424 (Pp/SIn region)
    float* dl   = p; p += (size_t)MROWS * DINNER;         // 4,071,424 (split-K small partials)
    float* xdbc = p; p += (size_t)MROWS * 64;             //   254,464
    unsigned short* Hh = (unsigned short*)p;              // h hi/lo (3976x512)
    unsigned short* Hl = Hh + (size_t)MROWS * DMODEL;
    p += (size_t)MROWS * DMODEL;
    unsigned short* XSh = (unsigned short*)p;             // smooth out hi/lo
    unsigned short* XSl = XSh + (size_t)BATCH * TLEN * NDIM;
    p += (size_t)BATCH * TLEN * NDIM;
    unsigned short* XCh = XSh;                            // alias: conv out hi/lo
    unsigned short* XCl = XCh + (size_t)MROWS * DINNER;
    float* xdreg = p;                                     // day-out region (4,096,000)
    unsigned short* XDh = (unsigned short*)p;
    unsigned short* XDl = XDh + (size_t)BATCH * TLEN * NDIM;
    p += (size_t)BATCH * TLEN * NDIM;
    unsigned short* Yh = XDh;                             // alias: scan out hi/lo
    unsigned short* Yl = Yh + (size_t)MROWS * DINNER;
    float* SEnd = xdreg;                                  // 25*8*16*1024 = 3,276,800 <= 4,096,000
    float* Pp   = xcv;                                    // 3,276,800 <= 4,071,424
    float* SIn  = Pp;                                     // in-place after scan_part2
    unsigned short* Wh = (unsigned short*)p;              // weight scratch hi/lo
    unsigned short* Wl = Wh + 1835008;
    p += 1835008;
    float* daybias = p; p += 2048;
    float* bigpart = xz;      // lin_in / out_proj split-K partials: 4 x 3976 x 512
    float* smlpart = dl;      // x_proj partials (8 x 3976 x 64); fc partials (4 x 3976 x 41)

    // 1. smooth -> XShl
    smooth_kernel<<<dim3((BATCH*TLEN*NDIM)/256), 256, 0, stream>>>(neuralInput, XSh, XSl);
    // 2. day weights repack + day GEMM (softsign) -> XDhl
    repack_day<<<dim3((8*65536)/256), 256, 0, stream>>>(day_w, day_b, dayIdx, Wh, Wl, daybias);
    mfma_gemm3<0,1,1,2,2,0><<<dim3(128, 2), 256, 0, stream>>>(
        XSh, XSl, 256, Wh, Wl, 256, nullptr, XDh, XDl, 256, daybias, 16000, 256, 256, 0);
    // 3. lin_in repack + split-K GEMM -> Hhl
    repack_linin<<<dim3((512*3584)/256), 256, 0, stream>>>(lin_in_w, Wh, Wl);
    mfma_gemm3<0,0,0,0,1,1><<<dim3(32, 4, 4), 256, 0, stream>>>(
        XDh, XDl, 0, Wh, Wl, 3584, bigpart, nullptr, nullptr, DMODEL, nullptr,
        MROWS, DMODEL, 3584, 896);
    reduce_k<0,1,1,0><<<dim3((MROWS*DMODEL)/256), 256, 0, stream>>>(
        bigpart, (size_t)MROWS*DMODEL, 4, nullptr, Hh, Hl, lin_in_b, DMODEL, MROWS*DMODEL);

    for (int l = 0; l < LAYERS; l++) {
        const float* ipw = in_proj_w  + (size_t)l * 2048 * DMODEL;
        const float* cwl = conv_w     + (size_t)l * DINNER * 4;
        const float* cbl = conv_b     + (size_t)l * DINNER;
        const float* xpw = x_proj_w   + (size_t)l * 64 * DINNER;
        const float* dtw = dt_w       + (size_t)l * DINNER * DTRANK;
        const float* dtb = dt_b       + (size_t)l * DINNER;
        const float* alg = A_log      + (size_t)l * DINNER * DSTATE;
        const float* dpl = D_param    + (size_t)l * DINNER;
        const float* opw = out_proj_w + (size_t)l * DMODEL * DINNER;

        // in_proj: (3976x512)@(2048x512)^T -> xz fp32
        convw_kernel<<<dim3((2048*512)/256), 256, 0, stream>>>(ipw, Wh, Wl, 2048*512);
        mfma_gemm3<1,0,0,0,0,0><<<dim3(32, 16), 256, 0, stream>>>(
            Hh, Hl, DMODEL, Wh, Wl, DMODEL, xz, nullptr, nullptr, 2048, nullptr,
            MROWS, 2048, DMODEL, 0);
        // conv + silu -> XChl (hilo only; scan recomputes conv on the fly)
        conv_silu_kernel<<<dim3((MROWS*DINNER)/256), 256, 0, stream>>>(xz, cwl, cbl, XCh, XCl);
        // x_proj: split-K 8 -> xdbc fp32
        convw_kernel<<<dim3((64*1024)/256), 256, 0, stream>>>(xpw, Wh, Wl, 64*1024);
        mfma_gemm3<0,0,0,0,0,1><<<dim3(32, 1, 8), 256, 0, stream>>>(
            XCh, XCl, DINNER, Wh, Wl, DINNER, smlpart, nullptr, nullptr, 64, nullptr,
            MROWS, 64, DINNER, 128);
        reduce_k<1,0,0,0><<<dim3((MROWS*64)/256), 256, 0, stream>>>(
            smlpart, (size_t)MROWS*64, 8, xdbc, nullptr, nullptr, nullptr, 64, MROWS*64);
        // chunked scan (fused dt + conv + gate) -> Yhl
        scan_part1<<<dim3(8*4*NCH), 256, 0, stream>>>(xz, xdbc, dtw, dtb, cwl, cbl, alg,
                                                      SEnd, Pp);
        scan_part2<<<dim3(512), 256, 0, stream>>>(SEnd, Pp);
        scan_part3<<<dim3(8*4*NCH), 256, 0, stream>>>(xz, xdbc, dtw, dtb, cwl, cbl, alg,
                                                      dpl, SIn, Yh, Yl);
        // out_proj: split-K 4 -> Hhl
        convw_kernel<<<dim3((512*1024)/256), 256, 0, stream>>>(opw, Wh, Wl, 512*1024);
        mfma_gemm3<0,0,0,0,0,1><<<dim3(32, 4, 4), 256, 0, stream>>>(
            Yh, Yl, DINNER, Wh, Wl, DINNER, bigpart, nullptr, nullptr, DMODEL, nullptr,
            MROWS, DMODEL, DINNER, 256);
        reduce_k<0,1,0,0><<<dim3((MROWS*DMODEL)/256), 256, 0, stream>>>(
            bigpart, (size_t)MROWS*DMODEL, 4, nullptr, Hh, Hl, nullptr, DMODEL, MROWS*DMODEL);
    }

    // fc: split-K 4 -> out (3976 x 41) fp32 + bias
    convw_kernel<<<dim3((NCLS*DMODEL+255)/256), 256, 0, stream>>>(fc_w, Wh, Wl, NCLS*DMODEL);
    mfma_gemm3<0,0,0,0,0,1><<<dim3(32, 1, 4), 256, 0, stream>>>(
        Hh, Hl, DMODEL, Wh, Wl, DMODEL, smlpart, nullptr, nullptr, NCLS, nullptr,
        MROWS, NCLS, DMODEL, 128);
    reduce_k<1,0,1,0><<<dim3((MROWS*NCLS+255)/256), 256, 0, stream>>>(
        smlpart, (size_t)MROWS*NCLS, 4, out, nullptr, nullptr, fc_b, NCLS, MROWS*NCLS);
}

// Round 6
// 970.255 us; speedup vs baseline: 4.2021x; 1.2727x over previous
//
#include <hip/hip_runtime.h>
#include <math.h>

#define NDIM    256
#define DMODEL  512
#define DSTATE  16
#define KLEN    14
#define DINNER  1024
#define DTRANK  32
#define BATCH   8
#define TLEN    2000
#define LOUT    497
#define MROWS   (BATCH*LOUT)   // 3976
#define NCLS    41
#define LAYERS  4
#define NCH     25
#define CSZ     20

typedef __attribute__((ext_vector_type(8))) short short8;
typedef __attribute__((ext_vector_type(4))) float floatx4;

// ---------------- bf16 split helpers (RNE) ----------------
__device__ inline unsigned short bf16_rne(float f) {
    unsigned int u = __float_as_uint(f);
    u += 0x7fffu + ((u >> 16) & 1u);
    return (unsigned short)(u >> 16);
}
__device__ inline float bf16_to_f(unsigned short h) {
    return __uint_as_float(((unsigned int)h) << 16);
}
__device__ inline void write_hilo(float v, unsigned short* ph, unsigned short* pl) {
    unsigned short h = bf16_rne(v);
    *ph = h;
    *pl = bf16_rne(v - bf16_to_f(h));
}

// ---------------- native-transcendental helpers ----------------
__device__ inline float fexp(float x)  { return __expf(x); }
__device__ inline float fsilu(float x) { return x * __frcp_rn(1.f + __expf(-x)); }
__device__ inline float fsoftplus(float x) {
    return fmaxf(x, 0.f) + __logf(1.f + __expf(-fabsf(x)));
}

__device__ inline void gload16(const unsigned short* g, unsigned short* l) {
    __builtin_amdgcn_global_load_lds((const __attribute__((address_space(1))) void*)g,
                                     (__attribute__((address_space(3))) void*)l,
                                     16, 0, 0);
}

// ---------------------------------------------------------------------------
// Gaussian smoothing -> bf16 hi/lo
// ---------------------------------------------------------------------------
__global__ __launch_bounds__(256) void smooth_kernel(const float* __restrict__ X,
                                                     unsigned short* __restrict__ XSh,
                                                     unsigned short* __restrict__ XSl)
{
    __shared__ float w[20];
    int tid = threadIdx.x;
    if (tid < 20) {
        float t = ((float)tid - 9.5f) * 0.5f;
        w[tid] = expf(-0.5f * t * t);
    }
    __syncthreads();
    float s = 0.f;
    #pragma unroll
    for (int j = 0; j < 20; j++) s += w[j];
    float inv = 1.f / s;

    int idx = blockIdx.x * 256 + tid;
    if (idx >= BATCH * TLEN * NDIM) return;
    int d  = idx & 255;
    int bt = idx >> 8;
    int b  = bt / TLEN;
    int tt = bt - b * TLEN;
    const float* Xb = X + ((size_t)b * TLEN) * NDIM + d;
    float acc = 0.f;
    #pragma unroll
    for (int j = 0; j < 20; j++) {
        int t2 = tt - 9 + j;
        if (t2 >= 0 && t2 < TLEN) acc += Xb[(size_t)t2 * NDIM] * w[j];
    }
    write_hilo(acc * inv, XSh + idx, XSl + idx);
}

// ---------------------------------------------------------------------------
// Repack day weights for the 8 selected days (transposed, hi/lo) + bias
// ---------------------------------------------------------------------------
__global__ __launch_bounds__(256) void repack_day(const float* __restrict__ day_w,
                                                  const float* __restrict__ day_b,
                                                  const int*   __restrict__ dayIdx,
                                                  unsigned short* __restrict__ Wh,
                                                  unsigned short* __restrict__ Wl,
                                                  float* __restrict__ biasbuf)
{
    int idx = blockIdx.x * 256 + threadIdx.x;   // 8*65536
    if (idx >= 8 * 65536) return;
    int b = idx >> 16;
    int rem = idx & 65535;
    int n = rem >> 8, k = rem & 255;
    int day = dayIdx[b];
    float v = day_w[(size_t)day * 65536 + (size_t)k * 256 + n];
    write_hilo(v, Wh + idx, Wl + idx);
    if (rem < 256) biasbuf[b * 256 + rem] = day_b[(size_t)day * 256 + rem];
}

// ---------------------------------------------------------------------------
// Repack lin_in_w with K reordered as kk' = r*256 + dd
// ---------------------------------------------------------------------------
__global__ __launch_bounds__(256) void repack_linin(const float* __restrict__ W,
                                                    unsigned short* __restrict__ Wh,
                                                    unsigned short* __restrict__ Wl)
{
    int idx = blockIdx.x * 256 + threadIdx.x;   // 512*3584
    if (idx >= 512 * 3584) return;
    int o = idx / 3584;
    int kk = idx - o * 3584;
    int r = kk >> 8, dd = kk & 255;
    float v = W[(size_t)o * 3584 + dd * 14 + r];
    write_hilo(v, Wh + idx, Wl + idx);
}

// ---------------------------------------------------------------------------
// Generic fp32 -> bf16 hi/lo conversion (weights)
// ---------------------------------------------------------------------------
__global__ __launch_bounds__(256) void convw_kernel(const float* __restrict__ src,
                                                    unsigned short* __restrict__ dh,
                                                    unsigned short* __restrict__ dl,
                                                    int n)
{
    int i = blockIdx.x * 256 + threadIdx.x;
    if (i < n) write_hilo(src[i], dh + i, dl + i);
}

// ---------------------------------------------------------------------------
// Fused bf16x3 MFMA GEMM: single K-pass, 4 LDS tiles, 48 MFMA per BK=32 step.
// ---------------------------------------------------------------------------
template<int WF32, int WHL, int BIASF, int ACT, int AMAP, int SPLIT>
__global__ __launch_bounds__(256) void mfma_gemm3(
    const unsigned short* __restrict__ Ah, const unsigned short* __restrict__ Al, int lda,
    const unsigned short* __restrict__ Bh, const unsigned short* __restrict__ Bl, int ldb,
    float* __restrict__ Cf, unsigned short* __restrict__ Ch, unsigned short* __restrict__ Cl,
    int ldc, const float* __restrict__ bias, int M, int N, int K, int Kc)
{
    __shared__ __align__(16) unsigned short AsH[4096];
    __shared__ __align__(16) unsigned short AsL[4096];
    __shared__ __align__(16) unsigned short BsH[4096];
    __shared__ __align__(16) unsigned short BsL[4096];
    const int tid  = threadIdx.x;
    const int wave = tid >> 6, lane = tid & 63;
    const int wm = wave & 1, wn = wave >> 1;
    const int row0 = blockIdx.x * 128, col0 = blockIdx.y * 128;

    if (AMAP == 2) {
        int bb = row0 >> 11;
        Bh += (size_t)bb * 65536; Bl += (size_t)bb * 65536; bias += bb * 256;
    }

    int k0 = 0, kend = K;
    if (SPLIT) {
        k0 = blockIdx.z * Kc;
        kend = min(K, k0 + Kc);
        Cf += (size_t)blockIdx.z * (size_t)M * ldc;
    }

    const int slot0 = wave * 2, slot1 = wave * 2 + 1;
    const int f0 = slot0 * 64 + lane, f1 = slot1 * 64 + lane;
    const int ar0 = f0 >> 2, ar1 = f1 >> 2;
    const int kc0 = ((f0 & 3) ^ (ar0 & 3)) * 8;
    const int kc1 = ((f1 & 3) ^ (ar1 & 3)) * 8;
    size_t abase0, abase1;
    {
        int r0 = row0 + ar0, r1 = row0 + ar1;
        if (AMAP == 0) {
            abase0 = (size_t)min(r0, M - 1) * lda + kc0;
            abase1 = (size_t)min(r1, M - 1) * lda + kc1;
        } else if (AMAP == 1) {
            int m0 = min(r0, M - 1), m1 = min(r1, M - 1);
            int b0 = m0 / 497, l0 = m0 - b0 * 497;
            int b1 = m1 / 497, l1 = m1 - b1 * 497;
            abase0 = ((size_t)(b0 * 2000 + l0 * 4) << 8) + kc0;
            abase1 = ((size_t)(b1 * 2000 + l1 * 4) << 8) + kc1;
        } else {
            int b0 = r0 >> 11, t0 = min(r0 & 2047, 1999);
            int b1 = r1 >> 11, t1 = min(r1 & 2047, 1999);
            abase0 = ((size_t)(b0 * 2000 + t0) << 8) + kc0;
            abase1 = ((size_t)(b1 * 2000 + t1) << 8) + kc1;
        }
    }
    size_t bbase0 = (size_t)min(col0 + ar0, N - 1) * ldb + kc0;
    size_t bbase1 = (size_t)min(col0 + ar1, N - 1) * ldb + kc1;

    floatx4 acc[4][4];
    #pragma unroll
    for (int i = 0; i < 4; i++)
        #pragma unroll
        for (int j = 0; j < 4; j++) acc[i][j] = (floatx4){0.f, 0.f, 0.f, 0.f};

    const int mr = lane & 15;
    const int sw = ((lane >> 4) ^ (mr & 3)) * 8;

    for (int kt = k0; kt < kend; kt += 32) {
        __syncthreads();
        gload16(Ah + abase0 + kt, &AsH[slot0 * 512]);
        gload16(Ah + abase1 + kt, &AsH[slot1 * 512]);
        gload16(Al + abase0 + kt, &AsL[slot0 * 512]);
        gload16(Al + abase1 + kt, &AsL[slot1 * 512]);
        gload16(Bh + bbase0 + kt, &BsH[slot0 * 512]);
        gload16(Bh + bbase1 + kt, &BsH[slot1 * 512]);
        gload16(Bl + bbase0 + kt, &BsL[slot0 * 512]);
        gload16(Bl + bbase1 + kt, &BsL[slot1 * 512]);
        __syncthreads();
        short8 ah4[4], al4[4], bh4[4], bl4[4];
        #pragma unroll
        for (int i = 0; i < 4; i++) {
            int off = (wm * 64 + i * 16 + mr) * 32 + sw;
            ah4[i] = *(const short8*)&AsH[off];
            al4[i] = *(const short8*)&AsL[off];
        }
        #pragma unroll
        for (int j = 0; j < 4; j++) {
            int off = (wn * 64 + j * 16 + mr) * 32 + sw;
            bh4[j] = *(const short8*)&BsH[off];
            bl4[j] = *(const short8*)&BsL[off];
        }
        #pragma unroll
        for (int i = 0; i < 4; i++)
            #pragma unroll
            for (int j = 0; j < 4; j++)
                acc[i][j] = __builtin_amdgcn_mfma_f32_16x16x32_bf16(ah4[i], bh4[j], acc[i][j], 0, 0, 0);
        #pragma unroll
        for (int i = 0; i < 4; i++)
            #pragma unroll
            for (int j = 0; j < 4; j++)
                acc[i][j] = __builtin_amdgcn_mfma_f32_16x16x32_bf16(ah4[i], bl4[j], acc[i][j], 0, 0, 0);
        #pragma unroll
        for (int i = 0; i < 4; i++)
            #pragma unroll
            for (int j = 0; j < 4; j++)
                acc[i][j] = __builtin_amdgcn_mfma_f32_16x16x32_bf16(al4[i], bh4[j], acc[i][j], 0, 0, 0);
    }

    const int rq = (lane >> 4) * 4;
    #pragma unroll
    for (int i = 0; i < 4; i++) {
        #pragma unroll
        for (int j = 0; j < 4; j++) {
            int colg = col0 + wn * 64 + j * 16 + mr;
            if (colg >= N) continue;
            #pragma unroll
            for (int r = 0; r < 4; r++) {
                int rowg = row0 + wm * 64 + i * 16 + rq + r;
                if (SPLIT) {
                    if (rowg < M) Cf[(size_t)rowg * ldc + colg] = acc[i][j][r];
                    continue;
                }
                int orow; bool rok;
                if (AMAP == 2) {
                    int bb = rowg >> 11, t = rowg & 2047;
                    rok = (t < 2000);
                    orow = bb * 2000 + t;
                } else { rok = (rowg < M); orow = rowg; }
                if (!rok) continue;
                float v = acc[i][j][r];
                if (BIASF) v += bias[colg];
                if (ACT == 1) v = fmaxf(v, 0.f) + log1pf(expf(-fabsf(v)));
                if (ACT == 2) v = v / (1.f + fabsf(v));
                size_t oidx = (size_t)orow * ldc + colg;
                if (WF32) Cf[oidx] = v;
                if (WHL)  write_hilo(v, Ch + oidx, Cl + oidx);
            }
        }
    }
}

// ---------------------------------------------------------------------------
// Split-K reduction + bias/act + fp32/hilo writes
// ---------------------------------------------------------------------------
template<int WF32, int WHL, int BIASF, int ACT>
__global__ __launch_bounds__(256) void reduce_k(const float* __restrict__ Cp,
                                                size_t pstride, int nsplit,
                                                float* __restrict__ Cf,
                                                unsigned short* __restrict__ Ch,
                                                unsigned short* __restrict__ Cl,
                                                const float* __restrict__ bias,
                                                int N, int total)
{
    int i = blockIdx.x * 256 + threadIdx.x;
    if (i >= total) return;
    float v = 0.f;
    for (int z = 0; z < nsplit; z++) v += Cp[(size_t)z * pstride + i];
    if (BIASF) v += bias[i % N];
    if (ACT == 1) v = fmaxf(v, 0.f) + log1pf(expf(-fabsf(v)));
    if (WF32) Cf[i] = v;
    if (WHL)  write_hilo(v, Ch + i, Cl + i);
}

// ---------------------------------------------------------------------------
// Causal depthwise conv (k=4) + bias + SiLU -> hi/lo only (x_proj A operand)
// ---------------------------------------------------------------------------
__global__ __launch_bounds__(256) void conv_silu_kernel(const float* __restrict__ XZ,
                                                        const float* __restrict__ cw,
                                                        const float* __restrict__ cb,
                                                        unsigned short* __restrict__ XCh,
                                                        unsigned short* __restrict__ XCl)
{
    int idx = blockIdx.x * 256 + threadIdx.x;   // 3976*1024
    if (idx >= MROWS * DINNER) return;
    int row = idx >> 10, c = idx & 1023;
    unsigned b = (unsigned)row / 497u;
    int l = row - (int)b * 497;
    float acc = cb[c];
    #pragma unroll
    for (int j = 0; j < 4; j++) {
        int lj = l - 3 + j;
        if (lj >= 0) acc += XZ[(size_t)(row - 3 + j) * 2048 + c] * cw[c * 4 + j];
    }
    write_hilo(fsilu(acc), XCh + idx, XCl + idx);
}

// ---------------------------------------------------------------------------
// Scan phase 1: dt-dot + softplus (stored to DV) + conv/SiLU + local scan.
// ---------------------------------------------------------------------------
__global__ __launch_bounds__(256) void scan_part1(const float* __restrict__ XZ,
                                                  const float* __restrict__ XDBC,
                                                  const float* __restrict__ dtw,
                                                  const float* __restrict__ dtb,
                                                  const float* __restrict__ cw,
                                                  const float* __restrict__ cb,
                                                  const float* __restrict__ Alog,
                                                  float* __restrict__ DV,
                                                  float* __restrict__ SEnd,
                                                  float* __restrict__ Pp)
{
    __shared__ float sR[CSZ][64];
    int tid = threadIdx.x;
    int bid = blockIdx.x;
    int c = bid % NCH; int r = bid / NCH;
    int db = r & 3, b = r >> 2;
    int d = db * 256 + tid;
    int t0 = c * CSZ;
    int tcnt = min(CSZ, LOUT - t0);
    int rowbase = b * LOUT + t0;

    int li = tid >> 4, lj = (tid & 15) * 4;
    if (li < tcnt)
        *(float4*)&sR[li][lj] = *(const float4*)(XDBC + (size_t)(rowbase + li) * 64 + lj);
    if (li + 16 < tcnt)
        *(float4*)&sR[li + 16][lj] = *(const float4*)(XDBC + (size_t)(rowbase + li + 16) * 64 + lj);
    __syncthreads();

    float w[32];
    #pragma unroll
    for (int k = 0; k < 8; k++)
        *(float4*)&w[k * 4] = *(const float4*)(dtw + (size_t)d * 32 + k * 4);
    float dtbv = dtb[d];
    float4 cwv = *(const float4*)(cw + (size_t)d * 4);
    float cbv = cb[d];

    float a[DSTATE], cum[DSTATE], s[DSTATE];
    #pragma unroll
    for (int n = 0; n < DSTATE; n++) {
        a[n] = -fexp(Alog[(size_t)d * DSTATE + n]);
        cum[n] = 1.f; s[n] = 0.f;
    }

    const float* Xp = XZ + d;   // x half, stride 2048
    float xm1 = 0.f, xm2 = 0.f, xm3 = 0.f;
    if (t0 >= 1) xm1 = Xp[(size_t)(rowbase - 1) * 2048];
    if (t0 >= 2) xm2 = Xp[(size_t)(rowbase - 2) * 2048];
    if (t0 >= 3) xm3 = Xp[(size_t)(rowbase - 3) * 2048];
    float xr = Xp[(size_t)rowbase * 2048];

    for (int tt = 0; tt < tcnt; tt++) {
        float xr_n = (tt + 1 < tcnt) ? Xp[(size_t)(rowbase + tt + 1) * 2048] : 0.f;
        float d0 = dtbv, d1 = 0.f, d2 = 0.f, d3 = 0.f;
        #pragma unroll
        for (int k = 0; k < 8; k++) {
            d0 = fmaf(sR[tt][4*k+0], w[4*k+0], d0);
            d1 = fmaf(sR[tt][4*k+1], w[4*k+1], d1);
            d2 = fmaf(sR[tt][4*k+2], w[4*k+2], d2);
            d3 = fmaf(sR[tt][4*k+3], w[4*k+3], d3);
        }
        float dot = (d0 + d1) + (d2 + d3);
        float dv = fsoftplus(dot);
        DV[(size_t)(rowbase + tt) * DINNER + d] = dv;
        float pre = cbv + cwv.x * xm3 + cwv.y * xm2 + cwv.z * xm1 + cwv.w * xr;
        float xv = fsilu(pre);
        float dx = dv * xv;
        #pragma unroll
        for (int n = 0; n < DSTATE; n++) {
            float e = fexp(dv * a[n]);
            cum[n] *= e;
            s[n] = fmaf(e, s[n], dx * sR[tt][32 + n]);
        }
        xm3 = xm2; xm2 = xm1; xm1 = xr; xr = xr_n;
    }
    size_t base = ((size_t)(c * 8 + b) * 16) * 1024 + d;
    #pragma unroll
    for (int n = 0; n < DSTATE; n++) {
        SEnd[base + (size_t)n * 1024] = s[n];
        Pp[base + (size_t)n * 1024]   = cum[n];
    }
}

// ---------------------------------------------------------------------------
// Scan phase 2: combine chunk summaries; SIn written in place over Pp.
// ---------------------------------------------------------------------------
__global__ __launch_bounds__(256) void scan_part2(const float* __restrict__ SEnd,
                                                  float* __restrict__ PS)
{
    int tid = threadIdx.x;
    int bid = blockIdx.x;           // 512 = 8b * 16n * 4db
    int db = bid & 3, n = (bid >> 2) & 15, b = bid >> 6;
    int d = db * 256 + tid;
    float s = 0.f;
    for (int c = 0; c < NCH; c++) {
        size_t idx = ((size_t)(c * 8 + b) * 16 + n) * 1024 + d;
        float pc = PS[idx];
        float se = SEnd[idx];
        PS[idx] = s;
        s = fmaf(pc, s, se);
    }
}

// ---------------------------------------------------------------------------
// Scan phase 3: dv loaded, conv recomputed, true incoming state, gated y out
// ---------------------------------------------------------------------------
__global__ __launch_bounds__(256) void scan_part3(const float* __restrict__ XZ,
                                                  const float* __restrict__ XDBC,
                                                  const float* __restrict__ DV,
                                                  const float* __restrict__ cw,
                                                  const float* __restrict__ cb,
                                                  const float* __restrict__ Alog,
                                                  const float* __restrict__ Dp,
                                                  const float* __restrict__ SIn,
                                                  unsigned short* __restrict__ Yh,
                                                  unsigned short* __restrict__ Yl)
{
    __shared__ float sR[CSZ][32];
    int tid = threadIdx.x;
    int bid = blockIdx.x;
    int c = bid % NCH; int r = bid / NCH;
    int db = r & 3, b = r >> 2;
    int d = db * 256 + tid;
    int t0 = c * CSZ;
    int tcnt = min(CSZ, LOUT - t0);
    int rowbase = b * LOUT + t0;

    // stage B/C (cols 32..63): 32 rows x 8 chunks of float4
    int li = tid >> 3, lj = (tid & 7) * 4;
    if (li < tcnt)
        *(float4*)&sR[li][lj] = *(const float4*)(XDBC + (size_t)(rowbase + li) * 64 + 32 + lj);
    __syncthreads();

    float4 cwv = *(const float4*)(cw + (size_t)d * 4);
    float cbv = cb[d];
    float dD = Dp[d];

    float a[DSTATE], s[DSTATE];
    size_t base = ((size_t)(c * 8 + b) * 16) * 1024 + d;
    #pragma unroll
    for (int n = 0; n < DSTATE; n++) {
        a[n] = -fexp(Alog[(size_t)d * DSTATE + n]);
        s[n] = SIn[base + (size_t)n * 1024];
    }

    const float* Xp = XZ + d;          // x half
    const float* Zp = XZ + 1024 + d;   // z half
    const float* Vp = DV + d;
    float xm1 = 0.f, xm2 = 0.f, xm3 = 0.f;
    if (t0 >= 1) xm1 = Xp[(size_t)(rowbase - 1) * 2048];
    if (t0 >= 2) xm2 = Xp[(size_t)(rowbase - 2) * 2048];
    if (t0 >= 3) xm3 = Xp[(size_t)(rowbase - 3) * 2048];
    float xr = Xp[(size_t)rowbase * 2048];
    float zr = Zp[(size_t)rowbase * 2048];
    float dv = Vp[(size_t)rowbase * 1024];

    for (int tt = 0; tt < tcnt; tt++) {
        float xr_n = 0.f, zr_n = 0.f, dv_n = 0.f;
        if (tt + 1 < tcnt) {
            xr_n = Xp[(size_t)(rowbase + tt + 1) * 2048];
            zr_n = Zp[(size_t)(rowbase + tt + 1) * 2048];
            dv_n = Vp[(size_t)(rowbase + tt + 1) * 1024];
        }
        float pre = cbv + cwv.x * xm3 + cwv.y * xm2 + cwv.z * xm1 + cwv.w * xr;
        float xv = fsilu(pre);
        float dx = dv * xv;
        float y = 0.f;
        #pragma unroll
        for (int n = 0; n < DSTATE; n++) {
            float e = fexp(dv * a[n]);
            s[n] = fmaf(e, s[n], dx * sR[tt][n]);
            y = fmaf(s[n], sR[tt][DSTATE + n], y);
        }
        float g = fsilu(zr);
        float yv = (y + xv * dD) * g;
        size_t row = (size_t)(rowbase + tt);
        write_hilo(yv, Yh + row * DINNER + d, Yl + row * DINNER + d);
        xm3 = xm2; xm2 = xm1; xm1 = xr; xr = xr_n; zr = zr_n; dv = dv_n;
    }
}

// ---------------------------------------------------------------------------
extern "C" void kernel_launch(void* const* d_in, const int* in_sizes, int n_in,
                              void* d_out, int out_size, void* d_ws, size_t ws_size,
                              hipStream_t stream)
{
    const float* neuralInput = (const float*)d_in[0];
    const int*   dayIdx      = (const int*)  d_in[1];
    const float* day_w       = (const float*)d_in[2];
    const float* day_b       = (const float*)d_in[3];
    const float* lin_in_w    = (const float*)d_in[4];
    const float* lin_in_b    = (const float*)d_in[5];
    const float* in_proj_w   = (const float*)d_in[6];
    const float* conv_w      = (const float*)d_in[7];
    const float* conv_b      = (const float*)d_in[8];
    const float* x_proj_w    = (const float*)d_in[9];
    const float* dt_w        = (const float*)d_in[10];
    const float* dt_b        = (const float*)d_in[11];
    const float* A_log       = (const float*)d_in[12];
    const float* D_param     = (const float*)d_in[13];
    const float* out_proj_w  = (const float*)d_in[14];
    const float* fc_w        = (const float*)d_in[15];
    const float* fc_b        = (const float*)d_in[16];
    float* out = (float*)d_out;

    // ---------------- workspace layout (floats) ----------------
    float* p = (float*)d_ws;
    float* xz   = p; p += (size_t)MROWS * 2048;           // 8,142,848
    float* xcv  = p; p += (size_t)MROWS * DINNER;         // 4,071,424 (Pp/SIn region)
    float* dl   = p; p += (size_t)MROWS * DINNER;         // 4,071,424 (x_proj partials / DV)
    float* xdbc = p; p += (size_t)MROWS * 64;             //   254,464
    unsigned short* Hh = (unsigned short*)p;              // h hi/lo (3976x512)
    unsigned short* Hl = Hh + (size_t)MROWS * DMODEL;
    p += (size_t)MROWS * DMODEL;
    unsigned short* XSh = (unsigned short*)p;             // smooth out hi/lo
    unsigned short* XSl = XSh + (size_t)BATCH * TLEN * NDIM;
    p += (size_t)BATCH * TLEN * NDIM;
    unsigned short* XCh = XSh;                            // alias: conv out hi/lo
    unsigned short* XCl = XCh + (size_t)MROWS * DINNER;
    float* xdreg = p;                                     // day-out region (4,096,000)
    unsigned short* XDh = (unsigned short*)p;
    unsigned short* XDl = XDh + (size_t)BATCH * TLEN * NDIM;
    p += (size_t)BATCH * TLEN * NDIM;
    unsigned short* Yh = XDh;                             // alias: scan out hi/lo
    unsigned short* Yl = Yh + (size_t)MROWS * DINNER;
    float* SEnd = xdreg;                                  // 25*8*16*1024 = 3,276,800
    float* Pp   = xcv;                                    // 3,276,800 <= 4,071,424
    float* SIn  = Pp;                                     // in-place after scan_part2
    float* DVb  = dl;                                     // dv store (3976x1024)
    unsigned short* Wh = (unsigned short*)p;              // weight scratch hi/lo
    unsigned short* Wl = Wh + 1835008;
    p += 1835008;
    float* daybias = p; p += 2048;
    float* bigpart = xz;      // lin_in / out_proj split-K partials: 4 x 3976 x 512
    float* smlpart = dl;      // x_proj partials (8 x 3976 x 64); fc partials (4 x 3976 x 41)

    // 1. smooth -> XShl
    smooth_kernel<<<dim3((BATCH*TLEN*NDIM)/256), 256, 0, stream>>>(neuralInput, XSh, XSl);
    // 2. day weights repack + day GEMM (softsign) -> XDhl
    repack_day<<<dim3((8*65536)/256), 256, 0, stream>>>(day_w, day_b, dayIdx, Wh, Wl, daybias);
    mfma_gemm3<0,1,1,2,2,0><<<dim3(128, 2), 256, 0, stream>>>(
        XSh, XSl, 256, Wh, Wl, 256, nullptr, XDh, XDl, 256, daybias, 16000, 256, 256, 0);
    // 3. lin_in repack + split-K GEMM -> Hhl
    repack_linin<<<dim3((512*3584)/256), 256, 0, stream>>>(lin_in_w, Wh, Wl);
    mfma_gemm3<0,0,0,0,1,1><<<dim3(32, 4, 4), 256, 0, stream>>>(
        XDh, XDl, 0, Wh, Wl, 3584, bigpart, nullptr, nullptr, DMODEL, nullptr,
        MROWS, DMODEL, 3584, 896);
    reduce_k<0,1,1,0><<<dim3((MROWS*DMODEL)/256), 256, 0, stream>>>(
        bigpart, (size_t)MROWS*DMODEL, 4, nullptr, Hh, Hl, lin_in_b, DMODEL, MROWS*DMODEL);

    for (int l = 0; l < LAYERS; l++) {
        const float* ipw = in_proj_w  + (size_t)l * 2048 * DMODEL;
        const float* cwl = conv_w     + (size_t)l * DINNER * 4;
        const float* cbl = conv_b     + (size_t)l * DINNER;
        const float* xpw = x_proj_w   + (size_t)l * 64 * DINNER;
        const float* dtw = dt_w       + (size_t)l * DINNER * DTRANK;
        const float* dtb = dt_b       + (size_t)l * DINNER;
        const float* alg = A_log      + (size_t)l * DINNER * DSTATE;
        const float* dpl = D_param    + (size_t)l * DINNER;
        const float* opw = out_proj_w + (size_t)l * DMODEL * DINNER;

        // in_proj: (3976x512)@(2048x512)^T -> xz fp32
        convw_kernel<<<dim3((2048*512)/256), 256, 0, stream>>>(ipw, Wh, Wl, 2048*512);
        mfma_gemm3<1,0,0,0,0,0><<<dim3(32, 16), 256, 0, stream>>>(
            Hh, Hl, DMODEL, Wh, Wl, DMODEL, xz, nullptr, nullptr, 2048, nullptr,
            MROWS, 2048, DMODEL, 0);
        // conv + silu -> XChl (hilo only; scan recomputes conv on the fly)
        conv_silu_kernel<<<dim3((MROWS*DINNER)/256), 256, 0, stream>>>(xz, cwl, cbl, XCh, XCl);
        // x_proj: split-K 8 -> xdbc fp32
        convw_kernel<<<dim3((64*1024)/256), 256, 0, stream>>>(xpw, Wh, Wl, 64*1024);
        mfma_gemm3<0,0,0,0,0,1><<<dim3(32, 1, 8), 256, 0, stream>>>(
            XCh, XCl, DINNER, Wh, Wl, DINNER, smlpart, nullptr, nullptr, 64, nullptr,
            MROWS, 64, DINNER, 128);
        reduce_k<1,0,0,0><<<dim3((MROWS*64)/256), 256, 0, stream>>>(
            smlpart, (size_t)MROWS*64, 8, xdbc, nullptr, nullptr, nullptr, 64, MROWS*64);
        // chunked scan (fused dt + conv + gate) -> Yhl ; dv cached in DVb
        scan_part1<<<dim3(8*4*NCH), 256, 0, stream>>>(xz, xdbc, dtw, dtb, cwl, cbl, alg,
                                                      DVb, SEnd, Pp);
        scan_part2<<<dim3(512), 256, 0, stream>>>(SEnd, Pp);
        scan_part3<<<dim3(8*4*NCH), 256, 0, stream>>>(xz, xdbc, DVb, cwl, cbl, alg,
                                                      dpl, SIn, Yh, Yl);
        // out_proj: split-K 4 -> Hhl
        convw_kernel<<<dim3((512*1024)/256), 256, 0, stream>>>(opw, Wh, Wl, 512*1024);
        mfma_gemm3<0,0,0,0,0,1><<<dim3(32, 4, 4), 256, 0, stream>>>(
            Yh, Yl, DINNER, Wh, Wl, DINNER, bigpart, nullptr, nullptr, DMODEL, nullptr,
            MROWS, DMODEL, DINNER, 256);
        reduce_k<0,1,0,0><<<dim3((MROWS*DMODEL)/256), 256, 0, stream>>>(
            bigpart, (size_t)MROWS*DMODEL, 4, nullptr, Hh, Hl, nullptr, DMODEL, MROWS*DMODEL);
    }

    // fc: split-K 4 -> out (3976 x 41) fp32 + bias
    convw_kernel<<<dim3((NCLS*DMODEL+255)/256), 256, 0, stream>>>(fc_w, Wh, Wl, NCLS*DMODEL);
    mfma_gemm3<0,0,0,0,0,1><<<dim3(32, 1, 4), 256, 0, stream>>>(
        Hh, Hl, DMODEL, Wh, Wl, DMODEL, smlpart, nullptr, nullptr, NCLS, nullptr,
        MROWS, NCLS, DMODEL, 128);
    reduce_k<1,0,1,0><<<dim3((MROWS*NCLS+255)/256), 256, 0, stream>>>(
        smlpart, (size_t)MROWS*NCLS, 4, out, nullptr, nullptr, fc_b, NCLS, MROWS*NCLS);
}

// Round 7
// 909.224 us; speedup vs baseline: 4.4842x; 1.0671x over previous
//
#include <hip/hip_runtime.h>
#include <math.h>

#define NDIM    256
#define DMODEL  512
#define DSTATE  16
#define KLEN    14
#define DINNER  1024
#define DTRANK  32
#define BATCH   8
#define TLEN    2000
#define LOUT    497
#define MROWS   (BATCH*LOUT)   // 3976
#define NCLS    41
#define LAYERS  4
#define NCH     25
#define CSZ     20

typedef __attribute__((ext_vector_type(8))) short short8;
typedef __attribute__((ext_vector_type(4))) float floatx4;

// ---------------- bf16 split helpers (RNE, for A-side producers) ----------------
__device__ inline unsigned short bf16_rne(float f) {
    unsigned int u = __float_as_uint(f);
    u += 0x7fffu + ((u >> 16) & 1u);
    return (unsigned short)(u >> 16);
}
__device__ inline float bf16_to_f(unsigned short h) {
    return __uint_as_float(((unsigned int)h) << 16);
}
__device__ inline void write_hilo(float v, unsigned short* ph, unsigned short* pl) {
    unsigned short h = bf16_rne(v);
    *ph = h;
    *pl = bf16_rne(v - bf16_to_f(h));
}

// ---------------- native-transcendental helpers ----------------
__device__ inline float fexp(float x)  { return __expf(x); }
__device__ inline float fsilu(float x) { return x * __frcp_rn(1.f + __expf(-x)); }
__device__ inline float fsoftplus(float x) {
    return fmaxf(x, 0.f) + __logf(1.f + __expf(-fabsf(x)));
}

__device__ inline void gload16(const unsigned short* g, unsigned short* l) {
    __builtin_amdgcn_global_load_lds((const __attribute__((address_space(1))) void*)g,
                                     (__attribute__((address_space(3))) void*)l,
                                     16, 0, 0);
}
__device__ inline void gload16f(const float* g, float* l) {
    __builtin_amdgcn_global_load_lds((const __attribute__((address_space(1))) void*)g,
                                     (__attribute__((address_space(3))) void*)l,
                                     16, 0, 0);
}

// ---------------------------------------------------------------------------
// Gaussian smoothing -> bf16 hi/lo
// ---------------------------------------------------------------------------
__global__ __launch_bounds__(256) void smooth_kernel(const float* __restrict__ X,
                                                     unsigned short* __restrict__ XSh,
                                                     unsigned short* __restrict__ XSl)
{
    __shared__ float w[20];
    int tid = threadIdx.x;
    if (tid < 20) {
        float t = ((float)tid - 9.5f) * 0.5f;
        w[tid] = expf(-0.5f * t * t);
    }
    __syncthreads();
    float s = 0.f;
    #pragma unroll
    for (int j = 0; j < 20; j++) s += w[j];
    float inv = 1.f / s;

    int idx = blockIdx.x * 256 + tid;
    if (idx >= BATCH * TLEN * NDIM) return;
    int d  = idx & 255;
    int bt = idx >> 8;
    int b  = bt / TLEN;
    int tt = bt - b * TLEN;
    const float* Xb = X + ((size_t)b * TLEN) * NDIM + d;
    float acc = 0.f;
    #pragma unroll
    for (int j = 0; j < 20; j++) {
        int t2 = tt - 9 + j;
        if (t2 >= 0 && t2 < TLEN) acc += Xb[(size_t)t2 * NDIM] * w[j];
    }
    write_hilo(acc * inv, XSh + idx, XSl + idx);
}

// ---------------------------------------------------------------------------
// Repack day weights for the 8 selected days (transposed, fp32) + bias
// ---------------------------------------------------------------------------
__global__ __launch_bounds__(256) void repack_day(const float* __restrict__ day_w,
                                                  const float* __restrict__ day_b,
                                                  const int*   __restrict__ dayIdx,
                                                  float* __restrict__ Wf,
                                                  float* __restrict__ biasbuf)
{
    int idx = blockIdx.x * 256 + threadIdx.x;   // 8*65536
    if (idx >= 8 * 65536) return;
    int b = idx >> 16;
    int rem = idx & 65535;
    int n = rem >> 8, k = rem & 255;
    int day = dayIdx[b];
    Wf[idx] = day_w[(size_t)day * 65536 + (size_t)k * 256 + n];
    if (rem < 256) biasbuf[b * 256 + rem] = day_b[(size_t)day * 256 + rem];
}

// ---------------------------------------------------------------------------
// Repack lin_in_w with K reordered as kk' = r*256 + dd (fp32)
// ---------------------------------------------------------------------------
__global__ __launch_bounds__(256) void repack_linin(const float* __restrict__ W,
                                                    float* __restrict__ Wf)
{
    int idx = blockIdx.x * 256 + threadIdx.x;   // 512*3584
    if (idx >= 512 * 3584) return;
    int o = idx / 3584;
    int kk = idx - o * 3584;
    int r = kk >> 8, dd = kk & 255;
    Wf[idx] = W[(size_t)o * 3584 + dd * 14 + r];
}

// ---------------------------------------------------------------------------
// Fused bf16x3 MFMA GEMM, BK=64, 96 MFMA per barrier.
// A: pre-split bf16 hi/lo. B: raw fp32, split in-kernel (trunc/trunc).
// LDS 64KB: AsH/AsL 16KB each + Bs fp32 32KB. XOR swizzles keep LDS balanced.
// ---------------------------------------------------------------------------
template<int WF32, int WHL, int BIASF, int ACT, int AMAP, int SPLIT>
__global__ __launch_bounds__(256, 2) void mfma_gemm3(
    const unsigned short* __restrict__ Ah, const unsigned short* __restrict__ Al, int lda,
    const float* __restrict__ Bf, int ldb,
    float* __restrict__ Cf, unsigned short* __restrict__ Ch, unsigned short* __restrict__ Cl,
    int ldc, const float* __restrict__ bias, int M, int N, int K, int Kc)
{
    __shared__ __align__(16) unsigned short AsH[128 * 64];
    __shared__ __align__(16) unsigned short AsL[128 * 64];
    __shared__ __align__(16) float Bs[128 * 64];
    const int tid  = threadIdx.x;
    const int wave = tid >> 6, lane = tid & 63;
    const int wm = wave & 1, wn = wave >> 1;
    const int mr = lane & 15, qh = lane >> 4;
    const int row0 = blockIdx.x * 128, col0 = blockIdx.y * 128;

    if (AMAP == 2) {
        int bb = row0 >> 11;
        Bf += (size_t)bb * 65536; bias += bb * 256;
    }

    int k0 = 0, kend = K;
    if (SPLIT) {
        k0 = blockIdx.z * Kc;
        kend = min(K, k0 + Kc);
        Cf += (size_t)blockIdx.z * (size_t)M * ldc;
    }

    // ---- staging address precompute ----
    // A tile: 128 rows x 64 bf16; 1024 chunks of 8 bf16; 4 chunks/wave/tile.
    size_t aoff[4];
    #pragma unroll
    for (int i2 = 0; i2 < 4; i2++) {
        int ch = wave * 256 + i2 * 64 + lane;
        int ar = ch >> 3, ap = ch & 7;
        int ak = (ap ^ (ar & 7)) * 8;       // swizzled bf16 offset in 64-k window
        int grow = row0 + ar;
        size_t base;
        if (AMAP == 0) {
            base = (size_t)min(grow, M - 1) * lda + ak;
        } else if (AMAP == 1) {
            int m = min(grow, M - 1);
            int b = m / 497, l = m - b * 497;
            base = ((size_t)(b * 2000 + l * 4) << 8) + ak;
        } else {
            int b = grow >> 11, t = min(grow & 2047, 1999);
            base = ((size_t)(b * 2000 + t) << 8) + ak;
        }
        aoff[i2] = base;
    }
    // B tile: 128 rows x 64 fp32; 2048 chunks of 4 fp32; 8 chunks/wave.
    size_t boff[8];
    #pragma unroll
    for (int i2 = 0; i2 < 8; i2++) {
        int ch = wave * 512 + i2 * 64 + lane;
        int br = ch >> 4, bp = ch & 15;
        int bk = (bp ^ (br & 15)) * 4;      // swizzled fp32 offset in 64-k window
        boff[i2] = (size_t)min(col0 + br, N - 1) * ldb + bk;
    }

    floatx4 acc[4][4];
    #pragma unroll
    for (int i = 0; i < 4; i++)
        #pragma unroll
        for (int j = 0; j < 4; j++) acc[i][j] = (floatx4){0.f, 0.f, 0.f, 0.f};

    for (int kt = k0; kt < kend; kt += 64) {
        __syncthreads();
        #pragma unroll
        for (int i2 = 0; i2 < 4; i2++)
            gload16(Ah + aoff[i2] + kt, &AsH[(wave * 256 + i2 * 64) * 8]);
        #pragma unroll
        for (int i2 = 0; i2 < 4; i2++)
            gload16(Al + aoff[i2] + kt, &AsL[(wave * 256 + i2 * 64) * 8]);
        #pragma unroll
        for (int i2 = 0; i2 < 8; i2++)
            gload16f(Bf + boff[i2] + kt, &Bs[(wave * 512 + i2 * 64) * 4]);
        __syncthreads();

        #pragma unroll
        for (int s = 0; s < 2; s++) {
            short8 ah4[4], al4[4], bh4[4], bl4[4];
            #pragma unroll
            for (int i = 0; i < 4; i++) {
                int ro = wm * 64 + i * 16 + mr;
                int ao = ro * 64 + (((s * 4 + qh) ^ (mr & 7)) * 8);
                ah4[i] = *(const short8*)&AsH[ao];
                al4[i] = *(const short8*)&AsL[ao];
            }
            #pragma unroll
            for (int j = 0; j < 4; j++) {
                int ro = wn * 64 + j * 16 + mr;
                int p1 = (s * 8 + 2 * qh) ^ mr;
                int p2 = (s * 8 + 2 * qh + 1) ^ mr;
                float4 x1 = *(const float4*)&Bs[ro * 64 + p1 * 4];
                float4 x2 = *(const float4*)&Bs[ro * 64 + p2 * 4];
                float f[8] = {x1.x, x1.y, x1.z, x1.w, x2.x, x2.y, x2.z, x2.w};
                unsigned int u[8], lo[8];
                #pragma unroll
                for (int e = 0; e < 8; e++) {
                    u[e] = __float_as_uint(f[e]);
                    lo[e] = __float_as_uint(f[e] - __uint_as_float(u[e] & 0xffff0000u));
                }
                union { unsigned int w4[4]; short8 s8; } ch_, cl_;
                #pragma unroll
                for (int e = 0; e < 4; e++) {
                    ch_.w4[e] = __builtin_amdgcn_perm(u[2*e+1],  u[2*e],  0x07060302u);
                    cl_.w4[e] = __builtin_amdgcn_perm(lo[2*e+1], lo[2*e], 0x07060302u);
                }
                bh4[j] = ch_.s8;
                bl4[j] = cl_.s8;
            }
            #pragma unroll
            for (int i = 0; i < 4; i++)
                #pragma unroll
                for (int j = 0; j < 4; j++)
                    acc[i][j] = __builtin_amdgcn_mfma_f32_16x16x32_bf16(ah4[i], bh4[j], acc[i][j], 0, 0, 0);
            #pragma unroll
            for (int i = 0; i < 4; i++)
                #pragma unroll
                for (int j = 0; j < 4; j++)
                    acc[i][j] = __builtin_amdgcn_mfma_f32_16x16x32_bf16(ah4[i], bl4[j], acc[i][j], 0, 0, 0);
            #pragma unroll
            for (int i = 0; i < 4; i++)
                #pragma unroll
                for (int j = 0; j < 4; j++)
                    acc[i][j] = __builtin_amdgcn_mfma_f32_16x16x32_bf16(al4[i], bh4[j], acc[i][j], 0, 0, 0);
        }
    }

    const int rq = qh * 4;
    #pragma unroll
    for (int i = 0; i < 4; i++) {
        #pragma unroll
        for (int j = 0; j < 4; j++) {
            int colg = col0 + wn * 64 + j * 16 + mr;
            if (colg >= N) continue;
            #pragma unroll
            for (int r = 0; r < 4; r++) {
                int rowg = row0 + wm * 64 + i * 16 + rq + r;
                if (SPLIT) {
                    if (rowg < M) Cf[(size_t)rowg * ldc + colg] = acc[i][j][r];
                    continue;
                }
                int orow; bool rok;
                if (AMAP == 2) {
                    int bb = rowg >> 11, t = rowg & 2047;
                    rok = (t < 2000);
                    orow = bb * 2000 + t;
                } else { rok = (rowg < M); orow = rowg; }
                if (!rok) continue;
                float v = acc[i][j][r];
                if (BIASF) v += bias[colg];
                if (ACT == 1) v = fmaxf(v, 0.f) + log1pf(expf(-fabsf(v)));
                if (ACT == 2) v = v / (1.f + fabsf(v));
                size_t oidx = (size_t)orow * ldc + colg;
                if (WF32) Cf[oidx] = v;
                if (WHL)  write_hilo(v, Ch + oidx, Cl + oidx);
            }
        }
    }
}

// ---------------------------------------------------------------------------
// Split-K reduction + bias/act + fp32/hilo writes
// ---------------------------------------------------------------------------
template<int WF32, int WHL, int BIASF, int ACT>
__global__ __launch_bounds__(256) void reduce_k(const float* __restrict__ Cp,
                                                size_t pstride, int nsplit,
                                                float* __restrict__ Cf,
                                                unsigned short* __restrict__ Ch,
                                                unsigned short* __restrict__ Cl,
                                                const float* __restrict__ bias,
                                                int N, int total)
{
    int i = blockIdx.x * 256 + threadIdx.x;
    if (i >= total) return;
    float v = 0.f;
    for (int z = 0; z < nsplit; z++) v += Cp[(size_t)z * pstride + i];
    if (BIASF) v += bias[i % N];
    if (ACT == 1) v = fmaxf(v, 0.f) + log1pf(expf(-fabsf(v)));
    if (WF32) Cf[i] = v;
    if (WHL)  write_hilo(v, Ch + i, Cl + i);
}

// ---------------------------------------------------------------------------
// Causal depthwise conv (k=4) + bias + SiLU -> hi/lo only (x_proj A operand)
// ---------------------------------------------------------------------------
__global__ __launch_bounds__(256) void conv_silu_kernel(const float* __restrict__ XZ,
                                                        const float* __restrict__ cw,
                                                        const float* __restrict__ cb,
                                                        unsigned short* __restrict__ XCh,
                                                        unsigned short* __restrict__ XCl)
{
    int idx = blockIdx.x * 256 + threadIdx.x;   // 3976*1024
    if (idx >= MROWS * DINNER) return;
    int row = idx >> 10, c = idx & 1023;
    unsigned b = (unsigned)row / 497u;
    int l = row - (int)b * 497;
    float acc = cb[c];
    #pragma unroll
    for (int j = 0; j < 4; j++) {
        int lj = l - 3 + j;
        if (lj >= 0) acc += XZ[(size_t)(row - 3 + j) * 2048 + c] * cw[c * 4 + j];
    }
    write_hilo(fsilu(acc), XCh + idx, XCl + idx);
}

// ---------------------------------------------------------------------------
// Scan phase 1: dt-dot + softplus (stored to DV) + conv/SiLU + local scan.
// ---------------------------------------------------------------------------
__global__ __launch_bounds__(256) void scan_part1(const float* __restrict__ XZ,
                                                  const float* __restrict__ XDBC,
                                                  const float* __restrict__ dtw,
                                                  const float* __restrict__ dtb,
                                                  const float* __restrict__ cw,
                                                  const float* __restrict__ cb,
                                                  const float* __restrict__ Alog,
                                                  float* __restrict__ DV,
                                                  float* __restrict__ SEnd,
                                                  float* __restrict__ Pp)
{
    __shared__ float sR[CSZ][64];
    int tid = threadIdx.x;
    int bid = blockIdx.x;
    int c = bid % NCH; int r = bid / NCH;
    int db = r & 3, b = r >> 2;
    int d = db * 256 + tid;
    int t0 = c * CSZ;
    int tcnt = min(CSZ, LOUT - t0);
    int rowbase = b * LOUT + t0;

    int li = tid >> 4, lj = (tid & 15) * 4;
    if (li < tcnt)
        *(float4*)&sR[li][lj] = *(const float4*)(XDBC + (size_t)(rowbase + li) * 64 + lj);
    if (li + 16 < tcnt)
        *(float4*)&sR[li + 16][lj] = *(const float4*)(XDBC + (size_t)(rowbase + li + 16) * 64 + lj);
    __syncthreads();

    float w[32];
    #pragma unroll
    for (int k = 0; k < 8; k++)
        *(float4*)&w[k * 4] = *(const float4*)(dtw + (size_t)d * 32 + k * 4);
    float dtbv = dtb[d];
    float4 cwv = *(const float4*)(cw + (size_t)d * 4);
    float cbv = cb[d];

    float a[DSTATE], cum[DSTATE], s[DSTATE];
    #pragma unroll
    for (int n = 0; n < DSTATE; n++) {
        a[n] = -fexp(Alog[(size_t)d * DSTATE + n]);
        cum[n] = 1.f; s[n] = 0.f;
    }

    const float* Xp = XZ + d;   // x half, stride 2048
    float xm1 = 0.f, xm2 = 0.f, xm3 = 0.f;
    if (t0 >= 1) xm1 = Xp[(size_t)(rowbase - 1) * 2048];
    if (t0 >= 2) xm2 = Xp[(size_t)(rowbase - 2) * 2048];
    if (t0 >= 3) xm3 = Xp[(size_t)(rowbase - 3) * 2048];
    float xr = Xp[(size_t)rowbase * 2048];

    for (int tt = 0; tt < tcnt; tt++) {
        float xr_n = (tt + 1 < tcnt) ? Xp[(size_t)(rowbase + tt + 1) * 2048] : 0.f;
        float d0 = dtbv, d1 = 0.f, d2 = 0.f, d3 = 0.f;
        #pragma unroll
        for (int k = 0; k < 8; k++) {
            d0 = fmaf(sR[tt][4*k+0], w[4*k+0], d0);
            d1 = fmaf(sR[tt][4*k+1], w[4*k+1], d1);
            d2 = fmaf(sR[tt][4*k+2], w[4*k+2], d2);
            d3 = fmaf(sR[tt][4*k+3], w[4*k+3], d3);
        }
        float dot = (d0 + d1) + (d2 + d3);
        float dv = fsoftplus(dot);
        DV[(size_t)(rowbase + tt) * DINNER + d] = dv;
        float pre = cbv + cwv.x * xm3 + cwv.y * xm2 + cwv.z * xm1 + cwv.w * xr;
        float xv = fsilu(pre);
        float dx = dv * xv;
        #pragma unroll
        for (int n = 0; n < DSTATE; n++) {
            float e = fexp(dv * a[n]);
            cum[n] *= e;
            s[n] = fmaf(e, s[n], dx * sR[tt][32 + n]);
        }
        xm3 = xm2; xm2 = xm1; xm1 = xr; xr = xr_n;
    }
    size_t base = ((size_t)(c * 8 + b) * 16) * 1024 + d;
    #pragma unroll
    for (int n = 0; n < DSTATE; n++) {
        SEnd[base + (size_t)n * 1024] = s[n];
        Pp[base + (size_t)n * 1024]   = cum[n];
    }
}

// ---------------------------------------------------------------------------
// Scan phase 2: combine chunk summaries; SIn written in place over Pp.
// ---------------------------------------------------------------------------
__global__ __launch_bounds__(256) void scan_part2(const float* __restrict__ SEnd,
                                                  float* __restrict__ PS)
{
    int tid = threadIdx.x;
    int bid = blockIdx.x;           // 512 = 8b * 16n * 4db
    int db = bid & 3, n = (bid >> 2) & 15, b = bid >> 6;
    int d = db * 256 + tid;
    float s = 0.f;
    for (int c = 0; c < NCH; c++) {
        size_t idx = ((size_t)(c * 8 + b) * 16 + n) * 1024 + d;
        float pc = PS[idx];
        float se = SEnd[idx];
        PS[idx] = s;
        s = fmaf(pc, s, se);
    }
}

// ---------------------------------------------------------------------------
// Scan phase 3: dv loaded, conv recomputed, true incoming state, gated y out
// ---------------------------------------------------------------------------
__global__ __launch_bounds__(256) void scan_part3(const float* __restrict__ XZ,
                                                  const float* __restrict__ XDBC,
                                                  const float* __restrict__ DV,
                                                  const float* __restrict__ cw,
                                                  const float* __restrict__ cb,
                                                  const float* __restrict__ Alog,
                                                  const float* __restrict__ Dp,
                                                  const float* __restrict__ SIn,
                                                  unsigned short* __restrict__ Yh,
                                                  unsigned short* __restrict__ Yl)
{
    __shared__ float sR[CSZ][32];
    int tid = threadIdx.x;
    int bid = blockIdx.x;
    int c = bid % NCH; int r = bid / NCH;
    int db = r & 3, b = r >> 2;
    int d = db * 256 + tid;
    int t0 = c * CSZ;
    int tcnt = min(CSZ, LOUT - t0);
    int rowbase = b * LOUT + t0;

    int li = tid >> 3, lj = (tid & 7) * 4;
    if (li < tcnt)
        *(float4*)&sR[li][lj] = *(const float4*)(XDBC + (size_t)(rowbase + li) * 64 + 32 + lj);
    __syncthreads();

    float4 cwv = *(const float4*)(cw + (size_t)d * 4);
    float cbv = cb[d];
    float dD = Dp[d];

    float a[DSTATE], s[DSTATE];
    size_t base = ((size_t)(c * 8 + b) * 16) * 1024 + d;
    #pragma unroll
    for (int n = 0; n < DSTATE; n++) {
        a[n] = -fexp(Alog[(size_t)d * DSTATE + n]);
        s[n] = SIn[base + (size_t)n * 1024];
    }

    const float* Xp = XZ + d;          // x half
    const float* Zp = XZ + 1024 + d;   // z half
    const float* Vp = DV + d;
    float xm1 = 0.f, xm2 = 0.f, xm3 = 0.f;
    if (t0 >= 1) xm1 = Xp[(size_t)(rowbase - 1) * 2048];
    if (t0 >= 2) xm2 = Xp[(size_t)(rowbase - 2) * 2048];
    if (t0 >= 3) xm3 = Xp[(size_t)(rowbase - 3) * 2048];
    float xr = Xp[(size_t)rowbase * 2048];
    float zr = Zp[(size_t)rowbase * 2048];
    float dv = Vp[(size_t)rowbase * 1024];

    for (int tt = 0; tt < tcnt; tt++) {
        float xr_n = 0.f, zr_n = 0.f, dv_n = 0.f;
        if (tt + 1 < tcnt) {
            xr_n = Xp[(size_t)(rowbase + tt + 1) * 2048];
            zr_n = Zp[(size_t)(rowbase + tt + 1) * 2048];
            dv_n = Vp[(size_t)(rowbase + tt + 1) * 1024];
        }
        float pre = cbv + cwv.x * xm3 + cwv.y * xm2 + cwv.z * xm1 + cwv.w * xr;
        float xv = fsilu(pre);
        float dx = dv * xv;
        float y = 0.f;
        #pragma unroll
        for (int n = 0; n < DSTATE; n++) {
            float e = fexp(dv * a[n]);
            s[n] = fmaf(e, s[n], dx * sR[tt][n]);
            y = fmaf(s[n], sR[tt][DSTATE + n], y);
        }
        float g = fsilu(zr);
        float yv = (y + xv * dD) * g;
        size_t row = (size_t)(rowbase + tt);
        write_hilo(yv, Yh + row * DINNER + d, Yl + row * DINNER + d);
        xm3 = xm2; xm2 = xm1; xm1 = xr; xr = xr_n; zr = zr_n; dv = dv_n;
    }
}

// ---------------------------------------------------------------------------
extern "C" void kernel_launch(void* const* d_in, const int* in_sizes, int n_in,
                              void* d_out, int out_size, void* d_ws, size_t ws_size,
                              hipStream_t stream)
{
    const float* neuralInput = (const float*)d_in[0];
    const int*   dayIdx      = (const int*)  d_in[1];
    const float* day_w       = (const float*)d_in[2];
    const float* day_b       = (const float*)d_in[3];
    const float* lin_in_w    = (const float*)d_in[4];
    const float* lin_in_b    = (const float*)d_in[5];
    const float* in_proj_w   = (const float*)d_in[6];
    const float* conv_w      = (const float*)d_in[7];
    const float* conv_b      = (const float*)d_in[8];
    const float* x_proj_w    = (const float*)d_in[9];
    const float* dt_w        = (const float*)d_in[10];
    const float* dt_b        = (const float*)d_in[11];
    const float* A_log       = (const float*)d_in[12];
    const float* D_param     = (const float*)d_in[13];
    const float* out_proj_w  = (const float*)d_in[14];
    const float* fc_w        = (const float*)d_in[15];
    const float* fc_b        = (const float*)d_in[16];
    float* out = (float*)d_out;

    // ---------------- workspace layout (floats) ----------------
    float* p = (float*)d_ws;
    float* xz   = p; p += (size_t)MROWS * 2048;           // 8,142,848
    float* xcv  = p; p += (size_t)MROWS * DINNER;         // 4,071,424 (Pp/SIn region)
    float* dl   = p; p += (size_t)MROWS * DINNER;         // 4,071,424 (x_proj partials / DV)
    float* xdbc = p; p += (size_t)MROWS * 64;             //   254,464
    unsigned short* Hh = (unsigned short*)p;              // h hi/lo (3976x512)
    unsigned short* Hl = Hh + (size_t)MROWS * DMODEL;
    p += (size_t)MROWS * DMODEL;
    unsigned short* XSh = (unsigned short*)p;             // smooth out hi/lo
    unsigned short* XSl = XSh + (size_t)BATCH * TLEN * NDIM;
    p += (size_t)BATCH * TLEN * NDIM;
    unsigned short* XCh = XSh;                            // alias: conv out hi/lo
    unsigned short* XCl = XCh + (size_t)MROWS * DINNER;
    float* xdreg = p;                                     // day-out region (4,096,000)
    unsigned short* XDh = (unsigned short*)p;
    unsigned short* XDl = XDh + (size_t)BATCH * TLEN * NDIM;
    p += (size_t)BATCH * TLEN * NDIM;
    unsigned short* Yh = XDh;                             // alias: scan out hi/lo
    unsigned short* Yl = Yh + (size_t)MROWS * DINNER;
    float* SEnd = xdreg;                                  // 25*8*16*1024 = 3,276,800
    float* Pp   = xcv;                                    // 3,276,800 <= 4,071,424
    float* SIn  = Pp;                                     // in-place after scan_part2
    float* DVb  = dl;                                     // dv store (3976x1024)
    float* Wf   = p; p += 1835008;                        // fp32 repack scratch
    float* daybias = p; p += 2048;
    float* bigpart = xz;      // lin_in / out_proj split-K partials: 4 x 3976 x 512
    float* smlpart = dl;      // x_proj partials (8 x 3976 x 64); fc partials (4 x 3976 x 41)

    // 1. smooth -> XShl
    smooth_kernel<<<dim3((BATCH*TLEN*NDIM)/256), 256, 0, stream>>>(neuralInput, XSh, XSl);
    // 2. day weights repack (fp32) + day GEMM (softsign) -> XDhl
    repack_day<<<dim3((8*65536)/256), 256, 0, stream>>>(day_w, day_b, dayIdx, Wf, daybias);
    mfma_gemm3<0,1,1,2,2,0><<<dim3(128, 2), 256, 0, stream>>>(
        XSh, XSl, 256, Wf, 256, nullptr, XDh, XDl, 256, daybias, 16000, 256, 256, 0);
    // 3. lin_in repack (fp32) + split-K GEMM -> Hhl
    repack_linin<<<dim3((512*3584)/256), 256, 0, stream>>>(lin_in_w, Wf);
    mfma_gemm3<0,0,0,0,1,1><<<dim3(32, 4, 4), 256, 0, stream>>>(
        XDh, XDl, 0, Wf, 3584, bigpart, nullptr, nullptr, DMODEL, nullptr,
        MROWS, DMODEL, 3584, 896);
    reduce_k<0,1,1,0><<<dim3((MROWS*DMODEL)/256), 256, 0, stream>>>(
        bigpart, (size_t)MROWS*DMODEL, 4, nullptr, Hh, Hl, lin_in_b, DMODEL, MROWS*DMODEL);

    for (int l = 0; l < LAYERS; l++) {
        const float* ipw = in_proj_w  + (size_t)l * 2048 * DMODEL;
        const float* cwl = conv_w     + (size_t)l * DINNER * 4;
        const float* cbl = conv_b     + (size_t)l * DINNER;
        const float* xpw = x_proj_w   + (size_t)l * 64 * DINNER;
        const float* dtw = dt_w       + (size_t)l * DINNER * DTRANK;
        const float* dtb = dt_b       + (size_t)l * DINNER;
        const float* alg = A_log      + (size_t)l * DINNER * DSTATE;
        const float* dpl = D_param    + (size_t)l * DINNER;
        const float* opw = out_proj_w + (size_t)l * DMODEL * DINNER;

        // in_proj: (3976x512)@(2048x512)^T -> xz fp32 (weights direct fp32)
        mfma_gemm3<1,0,0,0,0,0><<<dim3(32, 16), 256, 0, stream>>>(
            Hh, Hl, DMODEL, ipw, DMODEL, xz, nullptr, nullptr, 2048, nullptr,
            MROWS, 2048, DMODEL, 0);
        // conv + silu -> XChl (hilo only; scan recomputes conv on the fly)
        conv_silu_kernel<<<dim3((MROWS*DINNER)/256), 256, 0, stream>>>(xz, cwl, cbl, XCh, XCl);
        // x_proj: split-K 8 -> xdbc fp32 (weights direct)
        mfma_gemm3<0,0,0,0,0,1><<<dim3(32, 1, 8), 256, 0, stream>>>(
            XCh, XCl, DINNER, xpw, DINNER, smlpart, nullptr, nullptr, 64, nullptr,
            MROWS, 64, DINNER, 128);
        reduce_k<1,0,0,0><<<dim3((MROWS*64)/256), 256, 0, stream>>>(
            smlpart, (size_t)MROWS*64, 8, xdbc, nullptr, nullptr, nullptr, 64, MROWS*64);
        // chunked scan (fused dt + conv + gate) -> Yhl ; dv cached in DVb
        scan_part1<<<dim3(8*4*NCH), 256, 0, stream>>>(xz, xdbc, dtw, dtb, cwl, cbl, alg,
                                                      DVb, SEnd, Pp);
        scan_part2<<<dim3(512), 256, 0, stream>>>(SEnd, Pp);
        scan_part3<<<dim3(8*4*NCH), 256, 0, stream>>>(xz, xdbc, DVb, cwl, cbl, alg,
                                                      dpl, SIn, Yh, Yl);
        // out_proj: split-K 4 -> Hhl (weights direct)
        mfma_gemm3<0,0,0,0,0,1><<<dim3(32, 4, 4), 256, 0, stream>>>(
            Yh, Yl, DINNER, opw, DINNER, bigpart, nullptr, nullptr, DMODEL, nullptr,
            MROWS, DMODEL, DINNER, 256);
        reduce_k<0,1,0,0><<<dim3((MROWS*DMODEL)/256), 256, 0, stream>>>(
            bigpart, (size_t)MROWS*DMODEL, 4, nullptr, Hh, Hl, nullptr, DMODEL, MROWS*DMODEL);
    }

    // fc: split-K 4 -> out (3976 x 41) fp32 + bias (weights direct)
    mfma_gemm3<0,0,0,0,0,1><<<dim3(32, 1, 4), 256, 0, stream>>>(
        Hh, Hl, DMODEL, fc_w, DMODEL, smlpart, nullptr, nullptr, NCLS, nullptr,
        MROWS, NCLS, DMODEL, 128);
    reduce_k<1,0,1,0><<<dim3((MROWS*NCLS+255)/256), 256, 0, stream>>>(
        smlpart, (size_t)MROWS*NCLS, 4, out, nullptr, nullptr, fc_b, NCLS, MROWS*NCLS);
}